// Round 12
// baseline (1398.233 us; speedup 1.0000x reference)
//
#include <hip/hip_runtime.h>

#define T_LEN 4096
#define C_DIM 2048
#define REC 224          // packed record: 16x[a,b,k,r] bf16 128B | dec/y f32 64B | v bf16 32B
#define CH 64            // scan steps per LDS chunk (64*224 = 14336 B)
#define CHB (CH * REC)
// scan LDS layout (dynamic): raw[2][14336] | dummy 2048 | conv[2][24576] | guard 256
#define RAW0 0
#define DUMMY 28672
#define CONV0 30720
#define CONVSZ 24576
#define SCAN_LDS 80128

typedef __attribute__((ext_vector_type(4))) float f32x4;
typedef __attribute__((ext_vector_type(2))) float f32x2;
typedef __attribute__((ext_vector_type(8))) __bf16 bf16x8;
typedef __attribute__((ext_vector_type(8))) unsigned short u16x8;
typedef __attribute__((ext_vector_type(4))) unsigned int u32x4;
typedef __attribute__((ext_vector_type(2))) unsigned int u32x2;
typedef unsigned short u16;
typedef unsigned int u32;

typedef __attribute__((address_space(1))) const void* as1cv;
typedef __attribute__((address_space(3))) void* as3v;

__device__ __forceinline__ void gld16(const void* g, void* l) {
  __builtin_amdgcn_global_load_lds((as1cv)g, (as3v)l, 16, 0, 0);
}

__device__ __forceinline__ u16 f2bf(float f) {
  union { float f; unsigned u; } x; x.f = f;
  return (u16)((x.u + 0x7fffu + ((x.u >> 16) & 1u)) >> 16);
}
__device__ __forceinline__ float bflo(unsigned u) {
  union { unsigned u; float f; } x; x.u = u << 16; return x.f;
}
__device__ __forceinline__ float bfhi(unsigned u) {
  union { unsigned u; float f; } x; x.u = u & 0xffff0000u; return x.f;
}
// sum over a 16-lane row via DPP (xor1, xor2, row_ror:4, row_ror:8) — all lanes get the sum
__device__ __forceinline__ float red16(float x) {
  int a;
  a = __builtin_amdgcn_update_dpp(0, __builtin_bit_cast(int, x), 0xB1, 0xF, 0xF, true);
  x += __builtin_bit_cast(float, a);
  a = __builtin_amdgcn_update_dpp(0, __builtin_bit_cast(int, x), 0x4E, 0xF, 0xF, true);
  x += __builtin_bit_cast(float, a);
  a = __builtin_amdgcn_update_dpp(0, __builtin_bit_cast(int, x), 0x124, 0xF, 0xF, true);
  x += __builtin_bit_cast(float, a);
  a = __builtin_amdgcn_update_dpp(0, __builtin_bit_cast(int, x), 0x128, 0xF, 0xF, true);
  x += __builtin_bit_cast(float, a);
  return x;
}
__device__ __forceinline__ f32x4 red16v(f32x4 v) {
  v[0] = red16(v[0]); v[1] = red16(v[1]);
  v[2] = red16(v[2]); v[3] = red16(v[3]);
  return v;
}

// ---------------- weights fp32 -> bf16 (all four in one launch) ----------------
__global__ __launch_bounds__(256)
void conv_bf16_k(const float* __restrict__ s0, const float* __restrict__ s1,
                 const float* __restrict__ s2, const float* __restrict__ s3,
                 u16* __restrict__ d0) {
  const float* s = (blockIdx.y == 0) ? s0 : (blockIdx.y == 1) ? s1
                   : (blockIdx.y == 2) ? s2 : s3;
  u16* d = d0 + (size_t)blockIdx.y * 4194304;
  int i = (blockIdx.x * 256 + threadIdx.x) * 8;
  f32x4 a = *(const f32x4*)(s + i);
  f32x4 b = *(const f32x4*)(s + i + 4);
  u16x8 o;
  o[0] = f2bf(a[0]); o[1] = f2bf(a[1]); o[2] = f2bf(a[2]); o[3] = f2bf(a[3]);
  o[4] = f2bf(b[0]); o[5] = f2bf(b[1]); o[6] = f2bf(b[2]); o[7] = f2bf(b[3]);
  *(u16x8*)(d + i) = o;
}

// ---------------- LoRA-down matrices: (C x 8) -> (8 x C) fp32 transpose ----------------
__global__ __launch_bounds__(256)
void trans_lora_k(const float* __restrict__ w1, const float* __restrict__ a1,
                  const float* __restrict__ v1, const float* __restrict__ g1,
                  float* __restrict__ wt) {
  const float* s = (blockIdx.y == 0) ? w1 : (blockIdx.y == 1) ? a1
                   : (blockIdx.y == 2) ? v1 : g1;
  float* d = wt + (size_t)blockIdx.y * (8 * C_DIM);
  int c = blockIdx.x * 256 + threadIdx.x;    // grid.x = 8
  f32x4 lo = *(const f32x4*)(s + c * 8);
  f32x4 hi = *(const f32x4*)(s + c * 8 + 4);
  d[0 * C_DIM + c] = lo[0]; d[1 * C_DIM + c] = lo[1];
  d[2 * C_DIM + c] = lo[2]; d[3 * C_DIM + c] = lo[3];
  d[4 * C_DIM + c] = hi[0]; d[5 * C_DIM + c] = hi[1];
  d[6 * C_DIM + c] = hi[2]; d[7 * C_DIM + c] = hi[3];
}

// ---------------- mix + LoRA down (strided mapping, all loads coalesced) ----------------
__global__ __launch_bounds__(256)
void mix_lora_k(const float* __restrict__ x,
                const float* __restrict__ xrw, const float* __restrict__ xww,
                const float* __restrict__ xkw, const float* __restrict__ xvw,
                const float* __restrict__ xaw, const float* __restrict__ xgw,
                const float* __restrict__ wt,   // 4 transposed tables, 8xC each
                u16* __restrict__ xr_bf, u16* __restrict__ xk_bf,
                u16* __restrict__ xv_bf, float* __restrict__ lora8) {
  const int rr = blockIdx.x;
  const int t = rr & (T_LEN - 1);
  const int tid = threadIdx.x;
  const float* xrow = x + (size_t)rr * C_DIM;
  float wl[8], al[8], vl[8], gl[8];
  #pragma unroll
  for (int l = 0; l < 8; ++l) { wl[l] = 0.f; al[l] = 0.f; vl[l] = 0.f; gl[l] = 0.f; }
  #pragma unroll
  for (int ii = 0; ii < 8; ++ii) {
    const int c = ii * 256 + tid;
    float xi = xrow[c];
    float xpv = t ? xrow[c - C_DIM] : 0.f;
    float dx = xpv - xi;
    float xr_ = fmaf(dx, xrw[c], xi);
    float xw_ = fmaf(dx, xww[c], xi);
    float xk_ = fmaf(dx, xkw[c], xi);
    float xv_ = fmaf(dx, xvw[c], xi);
    float xa_ = fmaf(dx, xaw[c], xi);
    float xg_ = fmaf(dx, xgw[c], xi);
    xr_bf[(size_t)rr * C_DIM + c] = f2bf(xr_);
    xk_bf[(size_t)rr * C_DIM + c] = f2bf(xk_);
    xv_bf[(size_t)rr * C_DIM + c] = f2bf(xv_);
    #pragma unroll
    for (int l = 0; l < 8; ++l) {
      wl[l] = fmaf(xw_, wt[l * C_DIM + c], wl[l]);
      al[l] = fmaf(xa_, wt[16384 + l * C_DIM + c], al[l]);
      vl[l] = fmaf(xv_, wt[32768 + l * C_DIM + c], vl[l]);
      gl[l] = fmaf(xg_, wt[49152 + l * C_DIM + c], gl[l]);
    }
  }
  // row-reduce (16 lanes) all 32 partials via DPP — pure VALU
  f32x4 w03 = red16v((f32x4){wl[0], wl[1], wl[2], wl[3]});
  f32x4 w47 = red16v((f32x4){wl[4], wl[5], wl[6], wl[7]});
  f32x4 a03 = red16v((f32x4){al[0], al[1], al[2], al[3]});
  f32x4 a47 = red16v((f32x4){al[4], al[5], al[6], al[7]});
  f32x4 v03 = red16v((f32x4){vl[0], vl[1], vl[2], vl[3]});
  f32x4 v47 = red16v((f32x4){vl[4], vl[5], vl[6], vl[7]});
  f32x4 g03 = red16v((f32x4){gl[0], gl[1], gl[2], gl[3]});
  f32x4 g47 = red16v((f32x4){gl[4], gl[5], gl[6], gl[7]});
  __shared__ __attribute__((aligned(16))) float red2[16][32];
  const int row = tid >> 4;          // 16 rows of 16 lanes
  if ((tid & 15) == 0) {
    *(f32x4*)&red2[row][0] = w03;  *(f32x4*)&red2[row][4] = w47;
    *(f32x4*)&red2[row][8] = a03;  *(f32x4*)&red2[row][12] = a47;
    *(f32x4*)&red2[row][16] = v03; *(f32x4*)&red2[row][20] = v47;
    *(f32x4*)&red2[row][24] = g03; *(f32x4*)&red2[row][28] = g47;
  }
  __syncthreads();
  if (tid < 32) {
    float s = 0.f;
    #pragma unroll
    for (int r = 0; r < 16; ++r) s += red2[r][tid];
    int mat = tid >> 3;
    if (mat == 0) s = tanhf(s);
    else if (mat == 3) s = 1.f / (1.f + expf(-s));
    lora8[(size_t)rr * 32 + tid] = s;
  }
}

// ---------------- 256x256 8-wave double-buffered MFMA GEMM (counted vmcnt) ----------------
__device__ __forceinline__ int swzslot(int row, int slot) {
  return slot ^ ((row >> 1) & 3);
}

__global__ __launch_bounds__(512)
void gemm8_k(const u16* __restrict__ A0, const u16* __restrict__ A1,
             const u16* __restrict__ A2, const u16* __restrict__ B0,
             const u16* __restrict__ B1, const u16* __restrict__ B2,
             char* __restrict__ out, int pmode) {
  extern __shared__ __attribute__((aligned(16))) char smem[];
  u16* Asm = (u16*)smem;               // [db][kh][8192] u16  (64 KB)
  u16* Bsm = (u16*)(smem + 65536);     // [db][kh][8192] u16  (64 KB)
  const int z = blockIdx.z;
  const u16* A = (z == 0) ? A0 : (z == 1) ? A1 : A2;
  const u16* Bw = (z == 0) ? B0 : (z == 1) ? B1 : B2;
  const int sbase = (z == 0) ? 4 : (z == 1) ? 6 : 192;
  const int sstr = (z == 2) ? 2 : 8;
  const int tid = threadIdx.x;
  const int wv = tid >> 6, ln = tid & 63;
  const int wr = wv >> 2, wc = wv & 3;         // 2 x 4 wave grid
  const int row0 = blockIdx.y * 256, col0 = blockIdx.x * 256;
  const int s_rw = tid >> 2;
  const int s_slotL = (tid & 3) ^ ((s_rw >> 1) & 3);   // logical slot fetched
  int aoff[8], boff[4];
  #pragma unroll
  for (int m = 0; m < 8; ++m) {
    int row = wr * 128 + m * 16 + (ln & 15);
    aoff[m] = row * 32 + swzslot(row, ln >> 4) * 8;
  }
  #pragma unroll
  for (int n = 0; n < 4; ++n) {
    int row = wc * 64 + n * 16 + (ln & 15);
    boff[n] = row * 32 + swzslot(row, ln >> 4) * 8;
  }
  f32x4 acc[8][4];
  #pragma unroll
  for (int m = 0; m < 8; ++m)
    #pragma unroll
    for (int n = 0; n < 4; ++n) acc[m][n] = (f32x4){0.f, 0.f, 0.f, 0.f};

  auto abase = [&](int db, int kh) -> u16* { return Asm + (db * 2 + kh) * 8192; };
  auto bbase = [&](int db, int kh) -> u16* { return Bsm + (db * 2 + kh) * 8192; };
  auto stage1 = [&](const u16* src, int baserow, u16* lbase, int kh, int skt, int rblk) {
    const u16* g = src + (size_t)(baserow + rblk * 128 + s_rw) * 2048
                   + skt * 64 + kh * 32 + s_slotL * 8;
    gld16(g, lbase + rblk * 4096 + wv * 512);
  };
  auto khblock = [&](int db, int kh, int skt, bool doStage) {
    const u16* Ab = abase(db, kh);
    const u16* Bb = bbase(db, kh);
    const int sdb = db ^ 1;
    bf16x8 bf[4], af[4];
    #pragma unroll
    for (int n = 0; n < 4; ++n) bf[n] = *(const bf16x8*)(Bb + boff[n]);
    #pragma unroll
    for (int m = 0; m < 4; ++m) af[m] = *(const bf16x8*)(Ab + aoff[m]);
    if (doStage) {
      stage1(A, row0, abase(sdb, kh), kh, skt, 0);
      stage1(A, row0, abase(sdb, kh), kh, skt, 1);
    }
    __builtin_amdgcn_s_setprio(1);
    #pragma unroll
    for (int m = 0; m < 4; ++m)
      #pragma unroll
      for (int n = 0; n < 4; ++n)
        acc[m][n] = __builtin_amdgcn_mfma_f32_16x16x32_bf16(af[m], bf[n], acc[m][n], 0, 0, 0);
    __builtin_amdgcn_s_setprio(0);
    #pragma unroll
    for (int m = 0; m < 4; ++m) af[m] = *(const bf16x8*)(Ab + aoff[4 + m]);
    if (doStage) {
      stage1(Bw, col0, bbase(sdb, kh), kh, skt, 0);
      stage1(Bw, col0, bbase(sdb, kh), kh, skt, 1);
    }
    __builtin_amdgcn_s_setprio(1);
    #pragma unroll
    for (int m = 0; m < 4; ++m)
      #pragma unroll
      for (int n = 0; n < 4; ++n)
        acc[4 + m][n] = __builtin_amdgcn_mfma_f32_16x16x32_bf16(af[m], bf[n], acc[4 + m][n], 0, 0, 0);
    __builtin_amdgcn_s_setprio(0);
  };

  stage1(A, row0, abase(0, 0), 0, 0, 0); stage1(A, row0, abase(0, 0), 0, 0, 1);
  stage1(Bw, col0, bbase(0, 0), 0, 0, 0); stage1(Bw, col0, bbase(0, 0), 0, 0, 1);
  stage1(A, row0, abase(0, 1), 1, 0, 0); stage1(A, row0, abase(0, 1), 1, 0, 1);
  stage1(Bw, col0, bbase(0, 1), 1, 0, 0); stage1(Bw, col0, bbase(0, 1), 1, 0, 1);
  asm volatile("s_waitcnt vmcnt(4)" ::: "memory");
  __builtin_amdgcn_s_barrier();
  for (int kt = 0; kt < 31; ++kt) {
    const int db = kt & 1;
    khblock(db, 0, kt + 1, true);
    asm volatile("s_waitcnt vmcnt(4)" ::: "memory");
    __builtin_amdgcn_s_barrier();
    khblock(db, 1, kt + 1, true);
    asm volatile("s_waitcnt vmcnt(4)" ::: "memory");
    __builtin_amdgcn_s_barrier();
  }
  khblock(1, 0, 0, false);
  asm volatile("s_waitcnt vmcnt(0)" ::: "memory");
  __builtin_amdgcn_s_barrier();
  khblock(1, 1, 0, false);

  const int rowb = row0 + wr * 128 + ((ln >> 4) << 2);
  const int colb = col0 + wc * 64 + (ln & 15);
  #pragma unroll
  for (int m = 0; m < 8; ++m)
    #pragma unroll
    for (int n = 0; n < 4; ++n)
      #pragma unroll
      for (int qq = 0; qq < 4; ++qq) {
        int row = rowb + m * 16 + qq;
        int col = colb + n * 16;
        float val = acc[m][n][qq];
        if (pmode == 0) {
          ((float*)out)[(size_t)row * 2048 + col] = val;
        } else {
          int bq = row >> 12, tq = row & (T_LEN - 1);
          int hq = col >> 4, jq = col & 15;
          *(u16*)(out + (size_t)((bq * 128 + hq) * T_LEN + tq) * REC
                  + sbase + jq * sstr) = f2bf(val);
        }
      }
}

// ---------------- post-GEMM: LoRA-up, decay, v-mix, kk-norm -> packed ----------------
__global__ __launch_bounds__(256)
void post_gemm_k(const float* __restrict__ v_first, const float* __restrict__ lora8,
                 const float* __restrict__ w0, const float* __restrict__ w2,
                 const float* __restrict__ a0, const float* __restrict__ a2,
                 const float* __restrict__ v0, const float* __restrict__ v2,
                 const float* __restrict__ k_k, const float* __restrict__ k_a,
                 char* __restrict__ packed) {
  const int rr = blockIdx.x;
  const int bq = rr >> 12, tq = rr & (T_LEN - 1);
  const int tid = threadIdx.x, c0 = tid * 8;
  const int hq = tid >> 1, j0 = (tid & 1) * 8;
  char* pb = packed + (size_t)((bq * 128 + hq) * T_LEN + tq) * REC;
  u32x4 pk0 = *(const u32x4*)(pb + j0 * 8);
  u32x4 pk1 = *(const u32x4*)(pb + j0 * 8 + 16);
  u32x4 pk2 = *(const u32x4*)(pb + j0 * 8 + 32);
  u32x4 pk3 = *(const u32x4*)(pb + j0 * 8 + 48);
  u32x4 uv = *(const u32x4*)(pb + 192 + 2 * j0);
  float kraw[8], vraw[8];
  kraw[0] = bflo(pk0[1]); kraw[1] = bflo(pk0[3]);
  kraw[2] = bflo(pk1[1]); kraw[3] = bflo(pk1[3]);
  kraw[4] = bflo(pk2[1]); kraw[5] = bflo(pk2[3]);
  kraw[6] = bflo(pk3[1]); kraw[7] = bflo(pk3[3]);
  #pragma unroll
  for (int ii = 0; ii < 4; ++ii) {
    vraw[2 * ii] = bflo(uv[ii]); vraw[2 * ii + 1] = bfhi(uv[ii]);
  }
  float vf[8] __attribute__((aligned(16)));
  const float* vfp = v_first + (size_t)rr * C_DIM + c0;
  *(f32x4*)vf = *(const f32x4*)vfp;
  *(f32x4*)(vf + 4) = *(const f32x4*)(vfp + 4);
  const float* lo = lora8 + (size_t)rr * 32;
  float w8[8] __attribute__((aligned(16)));
  float a8[8] __attribute__((aligned(16)));
  float v8[8] __attribute__((aligned(16)));
  *(f32x4*)w8 = *(const f32x4*)lo;        *(f32x4*)(w8 + 4) = *(const f32x4*)(lo + 4);
  *(f32x4*)a8 = *(const f32x4*)(lo + 8);  *(f32x4*)(a8 + 4) = *(const f32x4*)(lo + 12);
  *(f32x4*)v8 = *(const f32x4*)(lo + 16); *(f32x4*)(v8 + 4) = *(const f32x4*)(lo + 20);
  float wr8[8] __attribute__((aligned(16)));
  float ar8[8] __attribute__((aligned(16)));
  float vr8[8] __attribute__((aligned(16)));
  *(f32x4*)wr8 = *(const f32x4*)(w0 + c0); *(f32x4*)(wr8 + 4) = *(const f32x4*)(w0 + c0 + 4);
  *(f32x4*)ar8 = *(const f32x4*)(a0 + c0); *(f32x4*)(ar8 + 4) = *(const f32x4*)(a0 + c0 + 4);
  *(f32x4*)vr8 = *(const f32x4*)(v0 + c0); *(f32x4*)(vr8 + 4) = *(const f32x4*)(v0 + c0 + 4);
  #pragma unroll
  for (int l = 0; l < 8; ++l) {
    float tw[8] __attribute__((aligned(16)));
    float ta[8] __attribute__((aligned(16)));
    float tv[8] __attribute__((aligned(16)));
    *(f32x4*)tw = *(const f32x4*)(w2 + (size_t)l * C_DIM + c0);
    *(f32x4*)(tw + 4) = *(const f32x4*)(w2 + (size_t)l * C_DIM + c0 + 4);
    *(f32x4*)ta = *(const f32x4*)(a2 + (size_t)l * C_DIM + c0);
    *(f32x4*)(ta + 4) = *(const f32x4*)(a2 + (size_t)l * C_DIM + c0 + 4);
    *(f32x4*)tv = *(const f32x4*)(v2 + (size_t)l * C_DIM + c0);
    *(f32x4*)(tv + 4) = *(const f32x4*)(v2 + (size_t)l * C_DIM + c0 + 4);
    #pragma unroll
    for (int ii = 0; ii < 8; ++ii) {
      wr8[ii] = fmaf(w8[l], tw[ii], wr8[ii]);
      ar8[ii] = fmaf(a8[l], ta[ii], ar8[ii]);
      vr8[ii] = fmaf(v8[l], tv[ii], vr8[ii]);
    }
  }
  float kk8[8] __attribute__((aligned(16)));
  float ka8[8] __attribute__((aligned(16)));
  *(f32x4*)kk8 = *(const f32x4*)(k_k + c0); *(f32x4*)(kk8 + 4) = *(const f32x4*)(k_k + c0 + 4);
  *(f32x4*)ka8 = *(const f32x4*)(k_a + c0); *(f32x4*)(ka8 + 4) = *(const f32x4*)(k_a + c0 + 4);
  float kk[8], av[8];
  float dec[8] __attribute__((aligned(16)));
  u16 wk[8];
  u16x8 wv2;
  float ss = 0.f;
  #pragma unroll
  for (int ii = 0; ii < 8; ++ii) {
    float w_ = -log1pf(expf(-wr8[ii])) - 0.5f;
    dec[ii] = expf(-expf(w_));
    float a_ = 1.f / (1.f + expf(-ar8[ii]));
    float vm = 1.f / (1.f + expf(-vr8[ii]));
    wv2[ii] = f2bf(fmaf(vf[ii] - vraw[ii], vm, vraw[ii]));
    kk[ii] = kraw[ii] * kk8[ii];
    ss = fmaf(kk[ii], kk[ii], ss);
    av[ii] = a_;
    wk[ii] = f2bf(kraw[ii] * fmaf(a_ - 1.f, ka8[ii], 1.f));
  }
  ss += __shfl_xor(ss, 1);
  ss += __shfl_xor(ss, 2);
  ss += __shfl_xor(ss, 4);
  float sc = 1.f / fmaxf(sqrtf(ss), 1e-8f);
  u16 wa[8], wb[8];
  #pragma unroll
  for (int ii = 0; ii < 8; ++ii) {
    float kn = kk[ii] * sc;
    wa[ii] = f2bf(-kn);
    wb[ii] = f2bf(kn * av[ii]);
  }
  u32x4 o0, o1, o2, o3;
  o0[0] = (u32)wa[0] | ((u32)wb[0] << 16); o0[1] = (u32)wk[0] | (pk0[1] & 0xffff0000u);
  o0[2] = (u32)wa[1] | ((u32)wb[1] << 16); o0[3] = (u32)wk[1] | (pk0[3] & 0xffff0000u);
  o1[0] = (u32)wa[2] | ((u32)wb[2] << 16); o1[1] = (u32)wk[2] | (pk1[1] & 0xffff0000u);
  o1[2] = (u32)wa[3] | ((u32)wb[3] << 16); o1[3] = (u32)wk[3] | (pk1[3] & 0xffff0000u);
  o2[0] = (u32)wa[4] | ((u32)wb[4] << 16); o2[1] = (u32)wk[4] | (pk2[1] & 0xffff0000u);
  o2[2] = (u32)wa[5] | ((u32)wb[5] << 16); o2[3] = (u32)wk[5] | (pk2[3] & 0xffff0000u);
  o3[0] = (u32)wa[6] | ((u32)wb[6] << 16); o3[1] = (u32)wk[6] | (pk3[1] & 0xffff0000u);
  o3[2] = (u32)wa[7] | ((u32)wb[7] << 16); o3[3] = (u32)wk[7] | (pk3[3] & 0xffff0000u);
  *(u32x4*)(pb + j0 * 8) = o0;
  *(u32x4*)(pb + j0 * 8 + 16) = o1;
  *(u32x4*)(pb + j0 * 8 + 32) = o2;
  *(u32x4*)(pb + j0 * 8 + 48) = o3;
  *(u16x8*)(pb + 192 + 2 * j0) = wv2;
  *(f32x4*)(pb + 128 + 4 * j0) = *(f32x4*)dec;
  *(f32x4*)(pb + 128 + 4 * j0 + 16) = *(f32x4*)(dec + 4);
}

// ---------------- RWKV7 scan: producer/consumer wave split (A/B barrier pairs) ----------------
// Waves 0-3: serial chain (1 elem/lane). Waves 4-7: stage raw + pre-convert to f32.
// Barrier A(c): ALL waves' chunk-c raw loads landed (fixes per-wave vmcnt race).
// Barrier B(c): conv[c] written + lgkm-retired.
__global__ __launch_bounds__(512)
void scan_k(char* __restrict__ packed) {
  extern __shared__ __attribute__((aligned(16))) char smem[];
  const int hb = blockIdx.x;
  const int tid = threadIdx.x;
  const int wv = tid >> 6, ln = tid & 63;
  char* src = packed + (size_t)hb * (T_LEN * REC);
  const int NC = T_LEN / CH;   // 64

  if (wv >= 4) {
    // -------- producer --------
    const int pw = wv - 4;
    const int pid = pw * 64 + ln;   // 0..255
    auto issue_chunk = [&](int cc) {
      char* rb = smem + RAW0 + (cc & 1) * CHB;
      const char* g = src + (size_t)cc * CHB;
      #pragma unroll
      for (int q = 0; q < 4; ++q) {
        int u = pw * 4 + q;
        if (u < 14) gld16(g + u * 1024 + ln * 16, rb + u * 1024);
        else        gld16(g + ln * 16, smem + DUMMY);   // uniform vmcnt filler
      }
    };
    auto convert = [&](int cc) {
      const char* rb = smem + RAW0 + (cc & 1) * CHB;
      char* cv = smem + CONV0 + (cc & 1) * CONVSZ;
      #pragma unroll
      for (int it = 0; it < 4; ++it) {
        int p = pid + it * 256;
        int t = p >> 4, jj = p & 15;
        u32x2 w = *(const u32x2*)(rb + t * 224 + jj * 8);
        f32x4 o;
        o[0] = bflo(w[0]); o[1] = bfhi(w[0]);
        o[2] = bflo(w[1]); o[3] = bfhi(w[1]);
        *(f32x4*)(cv + t * 256 + jj * 16) = o;
      }
      {
        int t = pid >> 2, q = pid & 3;
        f32x4 dv = *(const f32x4*)(rb + t * 224 + 128 + q * 16);
        *(f32x4*)(cv + 16384 + t * 64 + q * 16) = dv;
      }
      #pragma unroll
      for (int it = 0; it < 2; ++it) {
        int p = pid + it * 256;
        int t = p >> 3, i2 = p & 7;
        u32 w = *(const u32*)(rb + t * 224 + 192 + i2 * 4);
        f32x2 o; o[0] = bflo(w); o[1] = bfhi(w);
        *(f32x2*)(cv + 20480 + t * 64 + i2 * 8) = o;
      }
    };
    issue_chunk(0);
    issue_chunk(1);
    asm volatile("s_waitcnt vmcnt(4)" ::: "memory");
    __builtin_amdgcn_s_barrier();                     // A0: all chunk-0 loads done
    convert(0);
    asm volatile("s_waitcnt lgkmcnt(0)" ::: "memory");
    __builtin_amdgcn_s_barrier();                     // B0: conv0 ready
    for (int c = 0; c < NC; ++c) {
      if (c + 2 < NC) {
        issue_chunk(c + 2);
        asm volatile("s_waitcnt vmcnt(4)" ::: "memory");
      } else {
        asm volatile("s_waitcnt vmcnt(0)" ::: "memory");
      }
      if (c + 1 < NC) {
        __builtin_amdgcn_s_barrier();                 // A(c+1): chunk c+1 raw complete
        convert(c + 1);
        asm volatile("s_waitcnt lgkmcnt(0)" ::: "memory");
        __builtin_amdgcn_s_barrier();                 // B(c+1): conv ready
      }
    }
  } else {
    // -------- consumer --------
    const int j = ln & 15;
    const int i = wv * 4 + (ln >> 4);
    float S = 0.f;
    __builtin_amdgcn_s_barrier();   // A0
    __builtin_amdgcn_s_barrier();   // B0
    for (int c = 0; c < NC; ++c) {
      const char* cv = smem + CONV0 + (c & 1) * CONVSZ;
      const char* pA = cv + j * 16;            // f32x4 [a,b,k,r], +t*256
      const char* pd = cv + 16384 + j * 4;     // dec f32, +t*64
      const char* pv = cv + 20480 + i * 4;     // v f32, +t*64
      float* yg = (float*)(src + (size_t)c * CHB);
      f32x4 Aa = *(const f32x4*)(pA);
      float da = *(const float*)(pd);
      float va = *(const float*)(pv);
      f32x4 Ab = *(const f32x4*)(pA + 256);
      float db = *(const float*)(pd + 64);
      float vb = *(const float*)(pv + 64);
      for (int t = 0; t < CH; t += 2) {
        f32x4 nA = *(const f32x4*)(pA + (t + 2) * 256);
        float nd = *(const float*)(pd + (t + 2) * 64);
        float nv = *(const float*)(pv + (t + 2) * 64);
        {
          float sa = red16(S * Aa[0]);
          S = fmaf(S, da, fmaf(sa, Aa[1], va * Aa[2]));
          float yv = red16(S * Aa[3]);
          if (j == 0) yg[t * (REC / 4) + 32 + i] = yv;
        }
        Aa = nA; da = nd; va = nv;
        f32x4 nA2 = *(const f32x4*)(pA + (t + 3) * 256);
        float nd2 = *(const float*)(pd + (t + 3) * 64);
        float nv2 = *(const float*)(pv + (t + 3) * 64);
        {
          float sa = red16(S * Ab[0]);
          S = fmaf(S, db, fmaf(sa, Ab[1], vb * Ab[2]));
          float yv = red16(S * Ab[3]);
          if (j == 0) yg[(t + 1) * (REC / 4) + 32 + i] = yv;
        }
        Ab = nA2; db = nd2; vb = nv2;
      }
      if (c + 1 < NC) {
        __builtin_amdgcn_s_barrier();   // A(c+1)
        __builtin_amdgcn_s_barrier();   // B(c+1)
      }
    }
  }
}

// ---------------- GroupNorm + residual + gate -> bf16 ----------------
__global__ __launch_bounds__(256)
void post_gn_k(const char* __restrict__ packed, const float* __restrict__ lora8,
               const float* __restrict__ g2, const float* __restrict__ ln_g,
               const float* __restrict__ ln_b, const float* __restrict__ r_k,
               u16* __restrict__ og) {
  const int rr = blockIdx.x;
  const int bq = rr >> 12, tq = rr & (T_LEN - 1);
  const int tid = threadIdx.x, c0 = tid * 8;
  const int hq = tid >> 1, j0 = (tid & 1) * 8;
  const char* pb = packed + (size_t)((bq * 128 + hq) * T_LEN + tq) * REC;
  float rv[8], kv[8], vv[8];
  u32x4 pk0 = *(const u32x4*)(pb + j0 * 8);
  u32x4 pk1 = *(const u32x4*)(pb + j0 * 8 + 16);
  u32x4 pk2 = *(const u32x4*)(pb + j0 * 8 + 32);
  u32x4 pk3 = *(const u32x4*)(pb + j0 * 8 + 48);
  kv[0] = bflo(pk0[1]); rv[0] = bfhi(pk0[1]); kv[1] = bflo(pk0[3]); rv[1] = bfhi(pk0[3]);
  kv[2] = bflo(pk1[1]); rv[2] = bfhi(pk1[1]); kv[3] = bflo(pk1[3]); rv[3] = bfhi(pk1[3]);
  kv[4] = bflo(pk2[1]); rv[4] = bfhi(pk2[1]); kv[5] = bflo(pk2[3]); rv[5] = bfhi(pk2[3]);
  kv[6] = bflo(pk3[1]); rv[6] = bfhi(pk3[1]); kv[7] = bflo(pk3[3]); rv[7] = bfhi(pk3[3]);
  u32x4 uv = *(const u32x4*)(pb + 192 + 2 * j0);
  #pragma unroll
  for (int ii = 0; ii < 4; ++ii) {
    vv[2 * ii] = bflo(uv[ii]); vv[2 * ii + 1] = bfhi(uv[ii]);
  }
  f32x4 y0 = *(const f32x4*)(pb + 128 + 4 * j0);
  f32x4 y1 = *(const f32x4*)(pb + 128 + 4 * j0 + 16);
  float o[8];
  o[0] = y0[0]; o[1] = y0[1]; o[2] = y0[2]; o[3] = y0[3];
  o[4] = y1[0]; o[5] = y1[1]; o[6] = y1[2]; o[7] = y1[3];
  float g8[8] __attribute__((aligned(16)));
  const float* lo = lora8 + (size_t)rr * 32 + 24;
  *(f32x4*)g8 = *(const f32x4*)lo;
  *(f32x4*)(g8 + 4) = *(const f32x4*)(lo + 4);
  float gg8[8] __attribute__((aligned(16)));
  #pragma unroll
  for (int ii = 0; ii < 8; ++ii) gg8[ii] = 0.f;
  #pragma unroll
  for (int l = 0; l < 8; ++l) {
    float tg[8] __attribute__((aligned(16)));
    *(f32x4*)tg = *(const f32x4*)(g2 + (size_t)l * C_DIM + c0);
    *(f32x4*)(tg + 4) = *(const f32x4*)(g2 + (size_t)l * C_DIM + c0 + 4);
    #pragma unroll
    for (int ii = 0; ii < 8; ++ii) gg8[ii] = fmaf(g8[l], tg[ii], gg8[ii]);
  }
  float rk8[8] __attribute__((aligned(16)));
  float lg8[8] __attribute__((aligned(16)));
  float lb8[8] __attribute__((aligned(16)));
  *(f32x4*)rk8 = *(const f32x4*)(r_k + c0); *(f32x4*)(rk8 + 4) = *(const f32x4*)(r_k + c0 + 4);
  *(f32x4*)lg8 = *(const f32x4*)(ln_g + c0); *(f32x4*)(lg8 + 4) = *(const f32x4*)(ln_g + c0 + 4);
  *(f32x4*)lb8 = *(const f32x4*)(ln_b + c0); *(f32x4*)(lb8 + 4) = *(const f32x4*)(ln_b + c0 + 4);
  float s1 = 0.f, s2 = 0.f, srk = 0.f;
  #pragma unroll
  for (int ii = 0; ii < 8; ++ii) {
    s1 += o[ii];
    s2 = fmaf(o[ii], o[ii], s2);
    srk = fmaf(rv[ii] * kv[ii], rk8[ii], srk);
  }
  s1 += __shfl_xor(s1, 1); s1 += __shfl_xor(s1, 2); s1 += __shfl_xor(s1, 4);
  s2 += __shfl_xor(s2, 1); s2 += __shfl_xor(s2, 2); s2 += __shfl_xor(s2, 4);
  srk += __shfl_xor(srk, 1); srk += __shfl_xor(srk, 2); srk += __shfl_xor(srk, 4);
  float mu = s1 * (1.f / 64.f);
  float var = s2 * (1.f / 64.f) - mu * mu;
  float rstd = rsqrtf(var + 0.00064f);
  u16x8 ov;
  #pragma unroll
  for (int ii = 0; ii < 8; ++ii) {
    float on = fmaf((o[ii] - mu) * rstd, lg8[ii], lb8[ii]);
    float o2 = fmaf(srk, vv[ii], on);
    ov[ii] = f2bf(o2 * gg8[ii]);
  }
  *(u16x8*)(og + (size_t)rr * C_DIM + c0) = ov;
}

extern "C" void kernel_launch(void* const* d_in, const int* in_sizes, int n_in,
                              void* d_out, int out_size, void* d_ws, size_t ws_size,
                              hipStream_t stream) {
  (void)in_sizes; (void)n_in; (void)out_size;
  const float* x      = (const float*)d_in[0];
  const float* v_first= (const float*)d_in[1];
  const float* x_r    = (const float*)d_in[2];
  const float* x_w    = (const float*)d_in[3];
  const float* x_k    = (const float*)d_in[4];
  const float* x_v    = (const float*)d_in[5];
  const float* x_a    = (const float*)d_in[6];
  const float* x_g    = (const float*)d_in[7];
  const float* w0     = (const float*)d_in[8];
  const float* w1     = (const float*)d_in[9];
  const float* w2     = (const float*)d_in[10];
  const float* a0     = (const float*)d_in[11];
  const float* a1     = (const float*)d_in[12];
  const float* a2     = (const float*)d_in[13];
  const float* v0     = (const float*)d_in[14];
  const float* v1     = (const float*)d_in[15];
  const float* v2     = (const float*)d_in[16];
  const float* g1     = (const float*)d_in[17];
  const float* g2     = (const float*)d_in[18];
  const float* k_k    = (const float*)d_in[19];
  const float* k_a    = (const float*)d_in[20];
  const float* r_k    = (const float*)d_in[21];
  const float* Wr     = (const float*)d_in[22];
  const float* Wk     = (const float*)d_in[23];
  const float* Wv     = (const float*)d_in[24];
  const float* Wo     = (const float*)d_in[25];
  const float* ln_g   = (const float*)d_in[26];
  const float* ln_b   = (const float*)d_in[27];

  if (ws_size < 370147328ull) return;
  char* ws = (char*)d_ws;
  u16* Wr_bf = (u16*)(ws + 0);            //  8 MB each, contiguous (conv indexes)
  u16* Wk_bf = Wr_bf + 4194304;
  u16* Wv_bf = Wk_bf + 4194304;
  u16* Wo_bf = Wv_bf + 4194304;
  u16* xr_bf = (u16*)(ws + 33554432);     // 32 MB each
  u16* xk_bf = xr_bf + 16777216;
  u16* xv_bf = xk_bf + 16777216;
  float* lora8 = (float*)(ws + 134217728); // 1 MB
  char* packed = ws + 135266304;           // 224 MB
  float* wt = (float*)packed;              // transposed LoRA tables (256 KB),
                                           // consumed before gemms overwrite
  u16* og = xr_bf;                         // reuse (dead after r-GEMM)
  float* out = (float*)d_out;

  (void)hipFuncSetAttribute((const void*)gemm8_k,
                            hipFuncAttributeMaxDynamicSharedMemorySize, 131072);
  (void)hipFuncSetAttribute((const void*)scan_k,
                            hipFuncAttributeMaxDynamicSharedMemorySize, SCAN_LDS);

  conv_bf16_k<<<dim3(2048, 4), 256, 0, stream>>>(Wr, Wk, Wv, Wo, Wr_bf);
  trans_lora_k<<<dim3(8, 4), 256, 0, stream>>>(w1, a1, v1, g1, wt);

  mix_lora_k<<<8192, 256, 0, stream>>>(x, x_r, x_w, x_k, x_v, x_a, x_g,
                                       wt, xr_bf, xk_bf, xv_bf, lora8);

  gemm8_k<<<dim3(8, 32, 3), 512, 131072, stream>>>(xk_bf, xr_bf, xv_bf,
                                                   Wk_bf, Wr_bf, Wv_bf,
                                                   packed, 1);

  post_gemm_k<<<8192, 256, 0, stream>>>(v_first, lora8, w0, w2, a0, a2, v0, v2,
                                        k_k, k_a, packed);

  scan_k<<<256, 512, SCAN_LDS, stream>>>(packed);

  post_gn_k<<<8192, 256, 0, stream>>>(packed, lora8, g2, ln_g, ln_b, r_k, og);

  gemm8_k<<<dim3(8, 32, 1), 512, 131072, stream>>>(og, og, og,
                                                   Wo_bf, Wo_bf, Wo_bf,
                                                   (char*)out, 0);

  hipMemcpyAsync(out + 16777216, v_first, (size_t)16777216 * 4,
                 hipMemcpyDeviceToDevice, stream);
}

// Round 13
// 1281.153 us; speedup vs baseline: 1.0914x; 1.0914x over previous
//
#include <hip/hip_runtime.h>

#define T_LEN 4096
#define C_DIM 2048
#define REC 224          // packed record: 16x[a,b,k,r] bf16 128B | dec/y f32 64B | v bf16 32B
#define CH 64            // scan steps per LDS chunk (64*224 = 14336 B)
#define CHB (CH * REC)

typedef __attribute__((ext_vector_type(4))) float f32x4;
typedef __attribute__((ext_vector_type(8))) __bf16 bf16x8;
typedef __attribute__((ext_vector_type(8))) unsigned short u16x8;
typedef __attribute__((ext_vector_type(4))) unsigned int u32x4;
typedef __attribute__((ext_vector_type(2))) unsigned int u32x2;
typedef unsigned short u16;
typedef unsigned int u32;

typedef __attribute__((address_space(1))) const void* as1cv;
typedef __attribute__((address_space(3))) void* as3v;

__device__ __forceinline__ void gld16(const void* g, void* l) {
  __builtin_amdgcn_global_load_lds((as1cv)g, (as3v)l, 16, 0, 0);
}

__device__ __forceinline__ u16 f2bf(float f) {
  union { float f; unsigned u; } x; x.f = f;
  return (u16)((x.u + 0x7fffu + ((x.u >> 16) & 1u)) >> 16);
}
__device__ __forceinline__ float bflo(unsigned u) {
  union { unsigned u; float f; } x; x.u = u << 16; return x.f;
}
__device__ __forceinline__ float bfhi(unsigned u) {
  union { unsigned u; float f; } x; x.u = u & 0xffff0000u; return x.f;
}
// sum over a 16-lane row via DPP (xor1, xor2, row_ror:4, row_ror:8) — all lanes get the sum
__device__ __forceinline__ float red16(float x) {
  int a;
  a = __builtin_amdgcn_update_dpp(0, __builtin_bit_cast(int, x), 0xB1, 0xF, 0xF, true);
  x += __builtin_bit_cast(float, a);
  a = __builtin_amdgcn_update_dpp(0, __builtin_bit_cast(int, x), 0x4E, 0xF, 0xF, true);
  x += __builtin_bit_cast(float, a);
  a = __builtin_amdgcn_update_dpp(0, __builtin_bit_cast(int, x), 0x124, 0xF, 0xF, true);
  x += __builtin_bit_cast(float, a);
  a = __builtin_amdgcn_update_dpp(0, __builtin_bit_cast(int, x), 0x128, 0xF, 0xF, true);
  x += __builtin_bit_cast(float, a);
  return x;
}
__device__ __forceinline__ f32x4 red16v(f32x4 v) {
  v[0] = red16(v[0]); v[1] = red16(v[1]);
  v[2] = red16(v[2]); v[3] = red16(v[3]);
  return v;
}

// ---------------- weights fp32 -> bf16 (all four in one launch) ----------------
__global__ __launch_bounds__(256)
void conv_bf16_k(const float* __restrict__ s0, const float* __restrict__ s1,
                 const float* __restrict__ s2, const float* __restrict__ s3,
                 u16* __restrict__ d0) {
  const float* s = (blockIdx.y == 0) ? s0 : (blockIdx.y == 1) ? s1
                   : (blockIdx.y == 2) ? s2 : s3;
  u16* d = d0 + (size_t)blockIdx.y * 4194304;
  int i = (blockIdx.x * 256 + threadIdx.x) * 8;
  f32x4 a = *(const f32x4*)(s + i);
  f32x4 b = *(const f32x4*)(s + i + 4);
  u16x8 o;
  o[0] = f2bf(a[0]); o[1] = f2bf(a[1]); o[2] = f2bf(a[2]); o[3] = f2bf(a[3]);
  o[4] = f2bf(b[0]); o[5] = f2bf(b[1]); o[6] = f2bf(b[2]); o[7] = f2bf(b[3]);
  *(u16x8*)(d + i) = o;
}

// ---------------- LoRA-down matrices: (C x 8) -> (8 x C) fp32 transpose ----------------
__global__ __launch_bounds__(256)
void trans_lora_k(const float* __restrict__ w1, const float* __restrict__ a1,
                  const float* __restrict__ v1, const float* __restrict__ g1,
                  float* __restrict__ wt) {
  const float* s = (blockIdx.y == 0) ? w1 : (blockIdx.y == 1) ? a1
                   : (blockIdx.y == 2) ? v1 : g1;
  float* d = wt + (size_t)blockIdx.y * (8 * C_DIM);
  int c = blockIdx.x * 256 + threadIdx.x;    // grid.x = 8
  f32x4 lo = *(const f32x4*)(s + c * 8);
  f32x4 hi = *(const f32x4*)(s + c * 8 + 4);
  d[0 * C_DIM + c] = lo[0]; d[1 * C_DIM + c] = lo[1];
  d[2 * C_DIM + c] = lo[2]; d[3 * C_DIM + c] = lo[3];
  d[4 * C_DIM + c] = hi[0]; d[5 * C_DIM + c] = hi[1];
  d[6 * C_DIM + c] = hi[2]; d[7 * C_DIM + c] = hi[3];
}

// ---------------- mix + LoRA down (strided mapping, all loads coalesced) ----------------
__global__ __launch_bounds__(256)
void mix_lora_k(const float* __restrict__ x,
                const float* __restrict__ xrw, const float* __restrict__ xww,
                const float* __restrict__ xkw, const float* __restrict__ xvw,
                const float* __restrict__ xaw, const float* __restrict__ xgw,
                const float* __restrict__ wt,   // 4 transposed tables, 8xC each
                u16* __restrict__ xr_bf, u16* __restrict__ xk_bf,
                u16* __restrict__ xv_bf, float* __restrict__ lora8) {
  const int rr = blockIdx.x;
  const int t = rr & (T_LEN - 1);
  const int tid = threadIdx.x;
  const float* xrow = x + (size_t)rr * C_DIM;
  float wl[8], al[8], vl[8], gl[8];
  #pragma unroll
  for (int l = 0; l < 8; ++l) { wl[l] = 0.f; al[l] = 0.f; vl[l] = 0.f; gl[l] = 0.f; }
  #pragma unroll
  for (int ii = 0; ii < 8; ++ii) {
    const int c = ii * 256 + tid;
    float xi = xrow[c];
    float xpv = t ? xrow[c - C_DIM] : 0.f;
    float dx = xpv - xi;
    float xr_ = fmaf(dx, xrw[c], xi);
    float xw_ = fmaf(dx, xww[c], xi);
    float xk_ = fmaf(dx, xkw[c], xi);
    float xv_ = fmaf(dx, xvw[c], xi);
    float xa_ = fmaf(dx, xaw[c], xi);
    float xg_ = fmaf(dx, xgw[c], xi);
    xr_bf[(size_t)rr * C_DIM + c] = f2bf(xr_);
    xk_bf[(size_t)rr * C_DIM + c] = f2bf(xk_);
    xv_bf[(size_t)rr * C_DIM + c] = f2bf(xv_);
    #pragma unroll
    for (int l = 0; l < 8; ++l) {
      wl[l] = fmaf(xw_, wt[l * C_DIM + c], wl[l]);
      al[l] = fmaf(xa_, wt[16384 + l * C_DIM + c], al[l]);
      vl[l] = fmaf(xv_, wt[32768 + l * C_DIM + c], vl[l]);
      gl[l] = fmaf(xg_, wt[49152 + l * C_DIM + c], gl[l]);
    }
  }
  // row-reduce (16 lanes) all 32 partials via DPP — pure VALU
  f32x4 w03 = red16v((f32x4){wl[0], wl[1], wl[2], wl[3]});
  f32x4 w47 = red16v((f32x4){wl[4], wl[5], wl[6], wl[7]});
  f32x4 a03 = red16v((f32x4){al[0], al[1], al[2], al[3]});
  f32x4 a47 = red16v((f32x4){al[4], al[5], al[6], al[7]});
  f32x4 v03 = red16v((f32x4){vl[0], vl[1], vl[2], vl[3]});
  f32x4 v47 = red16v((f32x4){vl[4], vl[5], vl[6], vl[7]});
  f32x4 g03 = red16v((f32x4){gl[0], gl[1], gl[2], gl[3]});
  f32x4 g47 = red16v((f32x4){gl[4], gl[5], gl[6], gl[7]});
  __shared__ __attribute__((aligned(16))) float red2[16][32];
  const int row = tid >> 4;          // 16 rows of 16 lanes
  if ((tid & 15) == 0) {
    *(f32x4*)&red2[row][0] = w03;  *(f32x4*)&red2[row][4] = w47;
    *(f32x4*)&red2[row][8] = a03;  *(f32x4*)&red2[row][12] = a47;
    *(f32x4*)&red2[row][16] = v03; *(f32x4*)&red2[row][20] = v47;
    *(f32x4*)&red2[row][24] = g03; *(f32x4*)&red2[row][28] = g47;
  }
  __syncthreads();
  if (tid < 32) {
    float s = 0.f;
    #pragma unroll
    for (int r = 0; r < 16; ++r) s += red2[r][tid];
    int mat = tid >> 3;
    if (mat == 0) s = tanhf(s);
    else if (mat == 3) s = 1.f / (1.f + expf(-s));
    lora8[(size_t)rr * 32 + tid] = s;
  }
}

// ---------------- 256x256 8-wave double-buffered MFMA GEMM (counted vmcnt) ----------------
__device__ __forceinline__ int swzslot(int row, int slot) {
  return slot ^ ((row >> 1) & 3);
}

__global__ __launch_bounds__(512)
void gemm8_k(const u16* __restrict__ A0, const u16* __restrict__ A1,
             const u16* __restrict__ A2, const u16* __restrict__ B0,
             const u16* __restrict__ B1, const u16* __restrict__ B2,
             char* __restrict__ out, int pmode) {
  extern __shared__ __attribute__((aligned(16))) char smem[];
  u16* Asm = (u16*)smem;               // [db][kh][8192] u16  (64 KB)
  u16* Bsm = (u16*)(smem + 65536);     // [db][kh][8192] u16  (64 KB)
  const int z = blockIdx.z;
  const u16* A = (z == 0) ? A0 : (z == 1) ? A1 : A2;
  const u16* Bw = (z == 0) ? B0 : (z == 1) ? B1 : B2;
  const int sbase = (z == 0) ? 4 : (z == 1) ? 6 : 192;
  const int sstr = (z == 2) ? 2 : 8;
  const int tid = threadIdx.x;
  const int wv = tid >> 6, ln = tid & 63;
  const int wr = wv >> 2, wc = wv & 3;         // 2 x 4 wave grid
  // XCD-bijective swizzle of the 8x32 tile grid (nwg=256, 256%8==0)
  const int bid = blockIdx.x + (blockIdx.y << 3);
  const int sw = (bid & 7) * 32 + (bid >> 3);
  const int row0 = (sw >> 3) * 256, col0 = (sw & 7) * 256;
  const int s_rw = tid >> 2;
  const int s_slotL = (tid & 3) ^ ((s_rw >> 1) & 3);   // logical slot fetched
  int aoff[8], boff[4];
  #pragma unroll
  for (int m = 0; m < 8; ++m) {
    int row = wr * 128 + m * 16 + (ln & 15);
    aoff[m] = row * 32 + swzslot(row, ln >> 4) * 8;
  }
  #pragma unroll
  for (int n = 0; n < 4; ++n) {
    int row = wc * 64 + n * 16 + (ln & 15);
    boff[n] = row * 32 + swzslot(row, ln >> 4) * 8;
  }
  f32x4 acc[8][4];
  #pragma unroll
  for (int m = 0; m < 8; ++m)
    #pragma unroll
    for (int n = 0; n < 4; ++n) acc[m][n] = (f32x4){0.f, 0.f, 0.f, 0.f};

  auto abase = [&](int db, int kh) -> u16* { return Asm + (db * 2 + kh) * 8192; };
  auto bbase = [&](int db, int kh) -> u16* { return Bsm + (db * 2 + kh) * 8192; };
  auto stage1 = [&](const u16* src, int baserow, u16* lbase, int kh, int skt, int rblk) {
    const u16* g = src + (size_t)(baserow + rblk * 128 + s_rw) * 2048
                   + skt * 64 + kh * 32 + s_slotL * 8;
    gld16(g, lbase + rblk * 4096 + wv * 512);
  };
  auto khblock = [&](int db, int kh, int skt, bool doStage) {
    const u16* Ab = abase(db, kh);
    const u16* Bb = bbase(db, kh);
    const int sdb = db ^ 1;
    bf16x8 bf[4], af[4];
    #pragma unroll
    for (int n = 0; n < 4; ++n) bf[n] = *(const bf16x8*)(Bb + boff[n]);
    #pragma unroll
    for (int m = 0; m < 4; ++m) af[m] = *(const bf16x8*)(Ab + aoff[m]);
    if (doStage) {
      stage1(A, row0, abase(sdb, kh), kh, skt, 0);
      stage1(A, row0, abase(sdb, kh), kh, skt, 1);
    }
    __builtin_amdgcn_s_setprio(1);
    #pragma unroll
    for (int m = 0; m < 4; ++m)
      #pragma unroll
      for (int n = 0; n < 4; ++n)
        acc[m][n] = __builtin_amdgcn_mfma_f32_16x16x32_bf16(af[m], bf[n], acc[m][n], 0, 0, 0);
    __builtin_amdgcn_s_setprio(0);
    #pragma unroll
    for (int m = 0; m < 4; ++m) af[m] = *(const bf16x8*)(Ab + aoff[4 + m]);
    if (doStage) {
      stage1(Bw, col0, bbase(sdb, kh), kh, skt, 0);
      stage1(Bw, col0, bbase(sdb, kh), kh, skt, 1);
    }
    __builtin_amdgcn_s_setprio(1);
    #pragma unroll
    for (int m = 0; m < 4; ++m)
      #pragma unroll
      for (int n = 0; n < 4; ++n)
        acc[4 + m][n] = __builtin_amdgcn_mfma_f32_16x16x32_bf16(af[m], bf[n], acc[4 + m][n], 0, 0, 0);
    __builtin_amdgcn_s_setprio(0);
  };

  stage1(A, row0, abase(0, 0), 0, 0, 0); stage1(A, row0, abase(0, 0), 0, 0, 1);
  stage1(Bw, col0, bbase(0, 0), 0, 0, 0); stage1(Bw, col0, bbase(0, 0), 0, 0, 1);
  stage1(A, row0, abase(0, 1), 1, 0, 0); stage1(A, row0, abase(0, 1), 1, 0, 1);
  stage1(Bw, col0, bbase(0, 1), 1, 0, 0); stage1(Bw, col0, bbase(0, 1), 1, 0, 1);
  asm volatile("s_waitcnt vmcnt(4)" ::: "memory");
  __builtin_amdgcn_s_barrier();
  for (int kt = 0; kt < 31; ++kt) {
    const int db = kt & 1;
    khblock(db, 0, kt + 1, true);
    asm volatile("s_waitcnt vmcnt(4)" ::: "memory");
    __builtin_amdgcn_s_barrier();
    khblock(db, 1, kt + 1, true);
    asm volatile("s_waitcnt vmcnt(4)" ::: "memory");
    __builtin_amdgcn_s_barrier();
  }
  khblock(1, 0, 0, false);
  asm volatile("s_waitcnt vmcnt(0)" ::: "memory");
  __builtin_amdgcn_s_barrier();
  khblock(1, 1, 0, false);

  const int rowb = row0 + wr * 128 + ((ln >> 4) << 2);
  const int colb = col0 + wc * 64 + (ln & 15);
  #pragma unroll
  for (int m = 0; m < 8; ++m)
    #pragma unroll
    for (int n = 0; n < 4; ++n)
      #pragma unroll
      for (int qq = 0; qq < 4; ++qq) {
        int row = rowb + m * 16 + qq;
        int col = colb + n * 16;
        float val = acc[m][n][qq];
        if (pmode == 0) {
          ((float*)out)[(size_t)row * 2048 + col] = val;
        } else {
          int bq = row >> 12, tq = row & (T_LEN - 1);
          int hq = col >> 4, jq = col & 15;
          *(u16*)(out + (size_t)((bq * 128 + hq) * T_LEN + tq) * REC
                  + sbase + jq * sstr) = f2bf(val);
        }
      }
}

// ---------------- post-GEMM: LoRA-up, decay, v-mix, kk-norm -> packed ----------------
__global__ __launch_bounds__(256)
void post_gemm_k(const float* __restrict__ v_first, const float* __restrict__ lora8,
                 const float* __restrict__ w0, const float* __restrict__ w2,
                 const float* __restrict__ a0, const float* __restrict__ a2,
                 const float* __restrict__ v0, const float* __restrict__ v2,
                 const float* __restrict__ k_k, const float* __restrict__ k_a,
                 char* __restrict__ packed) {
  const int rr = blockIdx.x;
  const int bq = rr >> 12, tq = rr & (T_LEN - 1);
  const int tid = threadIdx.x, c0 = tid * 8;
  const int hq = tid >> 1, j0 = (tid & 1) * 8;
  char* pb = packed + (size_t)((bq * 128 + hq) * T_LEN + tq) * REC;
  u32x4 pk0 = *(const u32x4*)(pb + j0 * 8);
  u32x4 pk1 = *(const u32x4*)(pb + j0 * 8 + 16);
  u32x4 pk2 = *(const u32x4*)(pb + j0 * 8 + 32);
  u32x4 pk3 = *(const u32x4*)(pb + j0 * 8 + 48);
  u32x4 uv = *(const u32x4*)(pb + 192 + 2 * j0);
  float kraw[8], vraw[8];
  kraw[0] = bflo(pk0[1]); kraw[1] = bflo(pk0[3]);
  kraw[2] = bflo(pk1[1]); kraw[3] = bflo(pk1[3]);
  kraw[4] = bflo(pk2[1]); kraw[5] = bflo(pk2[3]);
  kraw[6] = bflo(pk3[1]); kraw[7] = bflo(pk3[3]);
  #pragma unroll
  for (int ii = 0; ii < 4; ++ii) {
    vraw[2 * ii] = bflo(uv[ii]); vraw[2 * ii + 1] = bfhi(uv[ii]);
  }
  float vf[8] __attribute__((aligned(16)));
  const float* vfp = v_first + (size_t)rr * C_DIM + c0;
  *(f32x4*)vf = *(const f32x4*)vfp;
  *(f32x4*)(vf + 4) = *(const f32x4*)(vfp + 4);
  const float* lo = lora8 + (size_t)rr * 32;
  float w8[8] __attribute__((aligned(16)));
  float a8[8] __attribute__((aligned(16)));
  float v8[8] __attribute__((aligned(16)));
  *(f32x4*)w8 = *(const f32x4*)lo;        *(f32x4*)(w8 + 4) = *(const f32x4*)(lo + 4);
  *(f32x4*)a8 = *(const f32x4*)(lo + 8);  *(f32x4*)(a8 + 4) = *(const f32x4*)(lo + 12);
  *(f32x4*)v8 = *(const f32x4*)(lo + 16); *(f32x4*)(v8 + 4) = *(const f32x4*)(lo + 20);
  float wr8[8] __attribute__((aligned(16)));
  float ar8[8] __attribute__((aligned(16)));
  float vr8[8] __attribute__((aligned(16)));
  *(f32x4*)wr8 = *(const f32x4*)(w0 + c0); *(f32x4*)(wr8 + 4) = *(const f32x4*)(w0 + c0 + 4);
  *(f32x4*)ar8 = *(const f32x4*)(a0 + c0); *(f32x4*)(ar8 + 4) = *(const f32x4*)(a0 + c0 + 4);
  *(f32x4*)vr8 = *(const f32x4*)(v0 + c0); *(f32x4*)(vr8 + 4) = *(const f32x4*)(v0 + c0 + 4);
  #pragma unroll
  for (int l = 0; l < 8; ++l) {
    float tw[8] __attribute__((aligned(16)));
    float ta[8] __attribute__((aligned(16)));
    float tv[8] __attribute__((aligned(16)));
    *(f32x4*)tw = *(const f32x4*)(w2 + (size_t)l * C_DIM + c0);
    *(f32x4*)(tw + 4) = *(const f32x4*)(w2 + (size_t)l * C_DIM + c0 + 4);
    *(f32x4*)ta = *(const f32x4*)(a2 + (size_t)l * C_DIM + c0);
    *(f32x4*)(ta + 4) = *(const f32x4*)(a2 + (size_t)l * C_DIM + c0 + 4);
    *(f32x4*)tv = *(const f32x4*)(v2 + (size_t)l * C_DIM + c0);
    *(f32x4*)(tv + 4) = *(const f32x4*)(v2 + (size_t)l * C_DIM + c0 + 4);
    #pragma unroll
    for (int ii = 0; ii < 8; ++ii) {
      wr8[ii] = fmaf(w8[l], tw[ii], wr8[ii]);
      ar8[ii] = fmaf(a8[l], ta[ii], ar8[ii]);
      vr8[ii] = fmaf(v8[l], tv[ii], vr8[ii]);
    }
  }
  float kk8[8] __attribute__((aligned(16)));
  float ka8[8] __attribute__((aligned(16)));
  *(f32x4*)kk8 = *(const f32x4*)(k_k + c0); *(f32x4*)(kk8 + 4) = *(const f32x4*)(k_k + c0 + 4);
  *(f32x4*)ka8 = *(const f32x4*)(k_a + c0); *(f32x4*)(ka8 + 4) = *(const f32x4*)(k_a + c0 + 4);
  float kk[8], av[8];
  float dec[8] __attribute__((aligned(16)));
  u16 wk[8];
  u16x8 wv2;
  float ss = 0.f;
  #pragma unroll
  for (int ii = 0; ii < 8; ++ii) {
    float w_ = -log1pf(expf(-wr8[ii])) - 0.5f;
    dec[ii] = expf(-expf(w_));
    float a_ = 1.f / (1.f + expf(-ar8[ii]));
    float vm = 1.f / (1.f + expf(-vr8[ii]));
    wv2[ii] = f2bf(fmaf(vf[ii] - vraw[ii], vm, vraw[ii]));
    kk[ii] = kraw[ii] * kk8[ii];
    ss = fmaf(kk[ii], kk[ii], ss);
    av[ii] = a_;
    wk[ii] = f2bf(kraw[ii] * fmaf(a_ - 1.f, ka8[ii], 1.f));
  }
  ss += __shfl_xor(ss, 1);
  ss += __shfl_xor(ss, 2);
  ss += __shfl_xor(ss, 4);
  float sc = 1.f / fmaxf(sqrtf(ss), 1e-8f);
  u16 wa[8], wb[8];
  #pragma unroll
  for (int ii = 0; ii < 8; ++ii) {
    float kn = kk[ii] * sc;
    wa[ii] = f2bf(-kn);
    wb[ii] = f2bf(kn * av[ii]);
  }
  u32x4 o0, o1, o2, o3;
  o0[0] = (u32)wa[0] | ((u32)wb[0] << 16); o0[1] = (u32)wk[0] | (pk0[1] & 0xffff0000u);
  o0[2] = (u32)wa[1] | ((u32)wb[1] << 16); o0[3] = (u32)wk[1] | (pk0[3] & 0xffff0000u);
  o1[0] = (u32)wa[2] | ((u32)wb[2] << 16); o1[1] = (u32)wk[2] | (pk1[1] & 0xffff0000u);
  o1[2] = (u32)wa[3] | ((u32)wb[3] << 16); o1[3] = (u32)wk[3] | (pk1[3] & 0xffff0000u);
  o2[0] = (u32)wa[4] | ((u32)wb[4] << 16); o2[1] = (u32)wk[4] | (pk2[1] & 0xffff0000u);
  o2[2] = (u32)wa[5] | ((u32)wb[5] << 16); o2[3] = (u32)wk[5] | (pk2[3] & 0xffff0000u);
  o3[0] = (u32)wa[6] | ((u32)wb[6] << 16); o3[1] = (u32)wk[6] | (pk3[1] & 0xffff0000u);
  o3[2] = (u32)wa[7] | ((u32)wb[7] << 16); o3[3] = (u32)wk[7] | (pk3[3] & 0xffff0000u);
  *(u32x4*)(pb + j0 * 8) = o0;
  *(u32x4*)(pb + j0 * 8 + 16) = o1;
  *(u32x4*)(pb + j0 * 8 + 32) = o2;
  *(u32x4*)(pb + j0 * 8 + 48) = o3;
  *(u16x8*)(pb + 192 + 2 * j0) = wv2;
  *(f32x4*)(pb + 128 + 4 * j0) = *(f32x4*)dec;
  *(f32x4*)(pb + 128 + 4 * j0 + 16) = *(f32x4*)(dec + 4);
}

// ---------------- sequential RWKV7 scan: 1 head / 4-wave block, 1 elem/lane ----------------
// r10 structure + full unroll (immediate LDS offsets) + LDS-staged y with
// coalesced per-chunk flush (no scattered global stores in the hot loop).
__device__ __forceinline__ void stage(const char* g, char* l, int wv, int ln) {
  gld16(g + wv * 1024 + ln * 16, l + wv * 1024);
  gld16(g + 4096 + wv * 1024 + ln * 16, l + 4096 + wv * 1024);
  gld16(g + 8192 + wv * 1024 + ln * 16, l + 8192 + wv * 1024);
  if (wv < 2) gld16(g + 12288 + wv * 1024 + ln * 16, l + 12288 + wv * 1024);
}

__global__ __launch_bounds__(256)
void scan_k(char* __restrict__ packed) {
  // 2 chunk halves + 1 KB pad so tail prefetch over-reads stay in-bounds
  __shared__ __attribute__((aligned(16))) char bufm[2 * CHB + 1024];
  __shared__ __attribute__((aligned(16))) float ybuf[CH * 16];
  const int hb = blockIdx.x;
  const int tid = threadIdx.x;
  const int wv = tid >> 6, ln = tid & 63;
  const int j = ln & 15;
  const int i = wv * 4 + (ln >> 4);
  char* src = packed + (size_t)hb * (T_LEN * REC);
  float S = 0.f;
  stage(src, bufm, wv, ln);
  const int NC = T_LEN / CH;
  for (int c = 0; c < NC; ++c) {
    asm volatile("s_waitcnt vmcnt(0)" ::: "memory");
    __syncthreads();
    if (c + 1 < NC)
      stage(src + (size_t)(c + 1) * CHB, bufm + ((c + 1) & 1) * CHB, wv, ln);
    const char* Bp = bufm + (c & 1) * CHB;
    const char* p0 = Bp + j * 8;         // [a|b][k|r] packet, +t*REC
    const char* pd = Bp + 128 + j * 4;   // dec f32
    const char* pv = Bp + 192 + i * 2;   // v bf16
    // preload steps 0,1
    u32x2 kA = *(const u32x2*)(p0);
    float dA = *(const float*)(pd);
    u32 vA = *(const u16*)(pv);
    u32x2 kB = *(const u32x2*)(p0 + REC);
    float dB = *(const float*)(pd + REC);
    u32 vB = *(const u16*)(pv + REC);
    #pragma unroll
    for (int t = 0; t < CH; t += 2) {
      // prefetch t+2 (over-reads land in pad, discarded at chunk restart)
      u32x2 nkA = *(const u32x2*)(p0 + (t + 2) * REC);
      float ndA = *(const float*)(pd + (t + 2) * REC);
      u32 nvA = *(const u16*)(pv + (t + 2) * REC);
      {
        float a_ = bflo(kA[0]), b_ = bfhi(kA[0]);
        float k_ = bflo(kA[1]), r_ = bfhi(kA[1]);
        float v_ = bflo(vA);
        float sa = red16(S * a_);
        S = fmaf(S, dA, fmaf(sa, b_, v_ * k_));
        float yv = red16(S * r_);
        if (j == 0) ybuf[t * 16 + i] = yv;
      }
      kA = nkA; dA = ndA; vA = nvA;
      // prefetch t+3
      u32x2 nkB = *(const u32x2*)(p0 + (t + 3) * REC);
      float ndB = *(const float*)(pd + (t + 3) * REC);
      u32 nvB = *(const u16*)(pv + (t + 3) * REC);
      {
        float a_ = bflo(kB[0]), b_ = bfhi(kB[0]);
        float k_ = bflo(kB[1]), r_ = bfhi(kB[1]);
        float v_ = bflo(vB);
        float sa = red16(S * a_);
        S = fmaf(S, dB, fmaf(sa, b_, v_ * k_));
        float yv = red16(S * r_);
        if (j == 0) ybuf[(t + 1) * 16 + i] = yv;
      }
      kB = nkB; dB = ndB; vB = nvB;
    }
    __syncthreads();
    // coalesced y flush: thread -> record tid>>2, 16B part tid&3
    {
      const int rec = tid >> 2, part = tid & 3;
      f32x4 y4 = *(const f32x4*)(ybuf + rec * 16 + part * 4);
      *(f32x4*)(src + (size_t)c * CHB + rec * REC + 128 + part * 16) = y4;
    }
  }
}

// ---------------- GroupNorm + residual + gate -> bf16 (coalesced module mapping) ----------------
// block = (batch z, module y of 4 heads, 4 consecutive t x). lane = one channel.
__global__ __launch_bounds__(256)
void post_gn_k(const char* __restrict__ packed, const float* __restrict__ lora8,
               const float* __restrict__ g2, const float* __restrict__ ln_g,
               const float* __restrict__ ln_b, const float* __restrict__ r_k,
               u16* __restrict__ og) {
  const int tg = blockIdx.x;          // 0..1023 (4 t each)
  const int mo = blockIdx.y;          // module 0..31 (64 channels)
  const int bq = blockIdx.z;
  const int tid = threadIdx.x;
  const int wv = tid >> 6, ln = tid & 63;
  const int t = tg * 4 + wv;
  const int cc = ln & 15;
  const int hq = mo * 4 + (ln >> 4);
  const int c = mo * 64 + ln;
  const char* pb = packed + (size_t)((bq * 128 + hq) * T_LEN + t) * REC;
  u32 kr = *(const u32*)(pb + cc * 8 + 4);
  float kv = bflo(kr), rv = bfhi(kr);
  float vv = bflo(*(const u16*)(pb + 192 + cc * 2));
  float o = *(const float*)(pb + 128 + cc * 4);
  const int rr = bq * T_LEN + t;
  const float* lo = lora8 + (size_t)rr * 32 + 24;
  float gg = 0.f;
  #pragma unroll
  for (int l = 0; l < 8; ++l) gg = fmaf(lo[l], g2[l * C_DIM + c], gg);
  float s1 = red16(o);
  float s2 = red16(o * o);
  float srk = red16(rv * kv * r_k[c]);
  s1 += __shfl_xor(s1, 16); s2 += __shfl_xor(s2, 16); srk += __shfl_xor(srk, 16);
  s1 += __shfl_xor(s1, 32); s2 += __shfl_xor(s2, 32); srk += __shfl_xor(srk, 32);
  float mu = s1 * (1.f / 64.f);
  float var = s2 * (1.f / 64.f) - mu * mu;
  float rstd = rsqrtf(var + 0.00064f);
  float on = fmaf((o - mu) * rstd, ln_g[c], ln_b[c]);
  float o2 = fmaf(srk, vv, on);
  og[(size_t)rr * C_DIM + c] = f2bf(o2 * gg);
}

extern "C" void kernel_launch(void* const* d_in, const int* in_sizes, int n_in,
                              void* d_out, int out_size, void* d_ws, size_t ws_size,
                              hipStream_t stream) {
  (void)in_sizes; (void)n_in; (void)out_size;
  const float* x      = (const float*)d_in[0];
  const float* v_first= (const float*)d_in[1];
  const float* x_r    = (const float*)d_in[2];
  const float* x_w    = (const float*)d_in[3];
  const float* x_k    = (const float*)d_in[4];
  const float* x_v    = (const float*)d_in[5];
  const float* x_a    = (const float*)d_in[6];
  const float* x_g    = (const float*)d_in[7];
  const float* w0     = (const float*)d_in[8];
  const float* w1     = (const float*)d_in[9];
  const float* w2     = (const float*)d_in[10];
  const float* a0     = (const float*)d_in[11];
  const float* a1     = (const float*)d_in[12];
  const float* a2     = (const float*)d_in[13];
  const float* v0     = (const float*)d_in[14];
  const float* v1     = (const float*)d_in[15];
  const float* v2     = (const float*)d_in[16];
  const float* g1     = (const float*)d_in[17];
  const float* g2     = (const float*)d_in[18];
  const float* k_k    = (const float*)d_in[19];
  const float* k_a    = (const float*)d_in[20];
  const float* r_k    = (const float*)d_in[21];
  const float* Wr     = (const float*)d_in[22];
  const float* Wk     = (const float*)d_in[23];
  const float* Wv     = (const float*)d_in[24];
  const float* Wo     = (const float*)d_in[25];
  const float* ln_g   = (const float*)d_in[26];
  const float* ln_b   = (const float*)d_in[27];

  if (ws_size < 370147328ull) return;
  char* ws = (char*)d_ws;
  u16* Wr_bf = (u16*)(ws + 0);            //  8 MB each, contiguous (conv indexes)
  u16* Wk_bf = Wr_bf + 4194304;
  u16* Wv_bf = Wk_bf + 4194304;
  u16* Wo_bf = Wv_bf + 4194304;
  u16* xr_bf = (u16*)(ws + 33554432);     // 32 MB each
  u16* xk_bf = xr_bf + 16777216;
  u16* xv_bf = xk_bf + 16777216;
  float* lora8 = (float*)(ws + 134217728); // 1 MB
  char* packed = ws + 135266304;           // 224 MB
  float* wt = (float*)packed;              // transposed LoRA tables (256 KB),
                                           // consumed before gemms overwrite
  u16* og = xr_bf;                         // reuse (dead after r-GEMM)
  float* out = (float*)d_out;

  (void)hipFuncSetAttribute((const void*)gemm8_k,
                            hipFuncAttributeMaxDynamicSharedMemorySize, 131072);

  conv_bf16_k<<<dim3(2048, 4), 256, 0, stream>>>(Wr, Wk, Wv, Wo, Wr_bf);
  trans_lora_k<<<dim3(8, 4), 256, 0, stream>>>(w1, a1, v1, g1, wt);

  mix_lora_k<<<8192, 256, 0, stream>>>(x, x_r, x_w, x_k, x_v, x_a, x_g,
                                       wt, xr_bf, xk_bf, xv_bf, lora8);

  gemm8_k<<<dim3(8, 32, 3), 512, 131072, stream>>>(xk_bf, xr_bf, xv_bf,
                                                   Wk_bf, Wr_bf, Wv_bf,
                                                   packed, 1);

  post_gemm_k<<<8192, 256, 0, stream>>>(v_first, lora8, w0, w2, a0, a2, v0, v2,
                                        k_k, k_a, packed);

  scan_k<<<256, 256, 0, stream>>>(packed);

  post_gn_k<<<dim3(1024, 32, 2), 256, 0, stream>>>(packed, lora8, g2,
                                                   ln_g, ln_b, r_k, og);

  gemm8_k<<<dim3(8, 32, 1), 512, 131072, stream>>>(og, og, og,
                                                   Wo_bf, Wo_bf, Wo_bf,
                                                   (char*)out, 0);

  hipMemcpyAsync(out + 16777216, v_first, (size_t)16777216 * 4,
                 hipMemcpyDeviceToDevice, stream);
}

// Round 14
// 1253.643 us; speedup vs baseline: 1.1153x; 1.0219x over previous
//
#include <hip/hip_runtime.h>

#define T_LEN 4096
#define C_DIM 2048
#define REC 224          // packed record: 16x[a,b,k,r] bf16 128B | dec/y f32 64B | v bf16 32B
#define CH 64            // scan steps per LDS chunk (64*224 = 14336 B)
#define CHB (CH * REC)

typedef __attribute__((ext_vector_type(4))) float f32x4;
typedef __attribute__((ext_vector_type(8))) __bf16 bf16x8;
typedef __attribute__((ext_vector_type(8))) unsigned short u16x8;
typedef __attribute__((ext_vector_type(4))) unsigned int u32x4;
typedef __attribute__((ext_vector_type(2))) unsigned int u32x2;
typedef unsigned short u16;
typedef unsigned int u32;

typedef __attribute__((address_space(1))) const void* as1cv;
typedef __attribute__((address_space(3))) void* as3v;

__device__ __forceinline__ void gld16(const void* g, void* l) {
  __builtin_amdgcn_global_load_lds((as1cv)g, (as3v)l, 16, 0, 0);
}

__device__ __forceinline__ u16 f2bf(float f) {
  union { float f; unsigned u; } x; x.f = f;
  return (u16)((x.u + 0x7fffu + ((x.u >> 16) & 1u)) >> 16);
}
__device__ __forceinline__ float bflo(unsigned u) {
  union { unsigned u; float f; } x; x.u = u << 16; return x.f;
}
__device__ __forceinline__ float bfhi(unsigned u) {
  union { unsigned u; float f; } x; x.u = u & 0xffff0000u; return x.f;
}
// sum over a 16-lane row via DPP (xor1, xor2, row_ror:4, row_ror:8) — all lanes get the sum
__device__ __forceinline__ float red16(float x) {
  int a;
  a = __builtin_amdgcn_update_dpp(0, __builtin_bit_cast(int, x), 0xB1, 0xF, 0xF, true);
  x += __builtin_bit_cast(float, a);
  a = __builtin_amdgcn_update_dpp(0, __builtin_bit_cast(int, x), 0x4E, 0xF, 0xF, true);
  x += __builtin_bit_cast(float, a);
  a = __builtin_amdgcn_update_dpp(0, __builtin_bit_cast(int, x), 0x124, 0xF, 0xF, true);
  x += __builtin_bit_cast(float, a);
  a = __builtin_amdgcn_update_dpp(0, __builtin_bit_cast(int, x), 0x128, 0xF, 0xF, true);
  x += __builtin_bit_cast(float, a);
  return x;
}
__device__ __forceinline__ f32x4 red16v(f32x4 v) {
  v[0] = red16(v[0]); v[1] = red16(v[1]);
  v[2] = red16(v[2]); v[3] = red16(v[3]);
  return v;
}

// ---------------- weights fp32 -> bf16 (all four in one launch) ----------------
__global__ __launch_bounds__(256)
void conv_bf16_k(const float* __restrict__ s0, const float* __restrict__ s1,
                 const float* __restrict__ s2, const float* __restrict__ s3,
                 u16* __restrict__ d0) {
  const float* s = (blockIdx.y == 0) ? s0 : (blockIdx.y == 1) ? s1
                   : (blockIdx.y == 2) ? s2 : s3;
  u16* d = d0 + (size_t)blockIdx.y * 4194304;
  int i = (blockIdx.x * 256 + threadIdx.x) * 8;
  f32x4 a = *(const f32x4*)(s + i);
  f32x4 b = *(const f32x4*)(s + i + 4);
  u16x8 o;
  o[0] = f2bf(a[0]); o[1] = f2bf(a[1]); o[2] = f2bf(a[2]); o[3] = f2bf(a[3]);
  o[4] = f2bf(b[0]); o[5] = f2bf(b[1]); o[6] = f2bf(b[2]); o[7] = f2bf(b[3]);
  *(u16x8*)(d + i) = o;
}

// ---------------- LoRA-down matrices: (C x 8) -> (8 x C) fp32 transpose ----------------
__global__ __launch_bounds__(256)
void trans_lora_k(const float* __restrict__ w1, const float* __restrict__ a1,
                  const float* __restrict__ v1, const float* __restrict__ g1,
                  float* __restrict__ wt) {
  const float* s = (blockIdx.y == 0) ? w1 : (blockIdx.y == 1) ? a1
                   : (blockIdx.y == 2) ? v1 : g1;
  float* d = wt + (size_t)blockIdx.y * (8 * C_DIM);
  int c = blockIdx.x * 256 + threadIdx.x;    // grid.x = 8
  f32x4 lo = *(const f32x4*)(s + c * 8);
  f32x4 hi = *(const f32x4*)(s + c * 8 + 4);
  d[0 * C_DIM + c] = lo[0]; d[1 * C_DIM + c] = lo[1];
  d[2 * C_DIM + c] = lo[2]; d[3 * C_DIM + c] = lo[3];
  d[4 * C_DIM + c] = hi[0]; d[5 * C_DIM + c] = hi[1];
  d[6 * C_DIM + c] = hi[2]; d[7 * C_DIM + c] = hi[3];
}

// ---------------- mix + LoRA down (strided mapping, all loads coalesced) ----------------
__global__ __launch_bounds__(256)
void mix_lora_k(const float* __restrict__ x,
                const float* __restrict__ xrw, const float* __restrict__ xww,
                const float* __restrict__ xkw, const float* __restrict__ xvw,
                const float* __restrict__ xaw, const float* __restrict__ xgw,
                const float* __restrict__ wt,   // 4 transposed tables, 8xC each
                u16* __restrict__ xr_bf, u16* __restrict__ xk_bf,
                u16* __restrict__ xv_bf, float* __restrict__ lora8) {
  const int rr = blockIdx.x;
  const int t = rr & (T_LEN - 1);
  const int tid = threadIdx.x;
  const float* xrow = x + (size_t)rr * C_DIM;
  float wl[8], al[8], vl[8], gl[8];
  #pragma unroll
  for (int l = 0; l < 8; ++l) { wl[l] = 0.f; al[l] = 0.f; vl[l] = 0.f; gl[l] = 0.f; }
  #pragma unroll
  for (int ii = 0; ii < 8; ++ii) {
    const int c = ii * 256 + tid;
    float xi = xrow[c];
    float xpv = t ? xrow[c - C_DIM] : 0.f;
    float dx = xpv - xi;
    float xr_ = fmaf(dx, xrw[c], xi);
    float xw_ = fmaf(dx, xww[c], xi);
    float xk_ = fmaf(dx, xkw[c], xi);
    float xv_ = fmaf(dx, xvw[c], xi);
    float xa_ = fmaf(dx, xaw[c], xi);
    float xg_ = fmaf(dx, xgw[c], xi);
    xr_bf[(size_t)rr * C_DIM + c] = f2bf(xr_);
    xk_bf[(size_t)rr * C_DIM + c] = f2bf(xk_);
    xv_bf[(size_t)rr * C_DIM + c] = f2bf(xv_);
    #pragma unroll
    for (int l = 0; l < 8; ++l) {
      wl[l] = fmaf(xw_, wt[l * C_DIM + c], wl[l]);
      al[l] = fmaf(xa_, wt[16384 + l * C_DIM + c], al[l]);
      vl[l] = fmaf(xv_, wt[32768 + l * C_DIM + c], vl[l]);
      gl[l] = fmaf(xg_, wt[49152 + l * C_DIM + c], gl[l]);
    }
  }
  // row-reduce (16 lanes) all 32 partials via DPP — pure VALU
  f32x4 w03 = red16v((f32x4){wl[0], wl[1], wl[2], wl[3]});
  f32x4 w47 = red16v((f32x4){wl[4], wl[5], wl[6], wl[7]});
  f32x4 a03 = red16v((f32x4){al[0], al[1], al[2], al[3]});
  f32x4 a47 = red16v((f32x4){al[4], al[5], al[6], al[7]});
  f32x4 v03 = red16v((f32x4){vl[0], vl[1], vl[2], vl[3]});
  f32x4 v47 = red16v((f32x4){vl[4], vl[5], vl[6], vl[7]});
  f32x4 g03 = red16v((f32x4){gl[0], gl[1], gl[2], gl[3]});
  f32x4 g47 = red16v((f32x4){gl[4], gl[5], gl[6], gl[7]});
  __shared__ __attribute__((aligned(16))) float red2[16][32];
  const int row = tid >> 4;          // 16 rows of 16 lanes
  if ((tid & 15) == 0) {
    *(f32x4*)&red2[row][0] = w03;  *(f32x4*)&red2[row][4] = w47;
    *(f32x4*)&red2[row][8] = a03;  *(f32x4*)&red2[row][12] = a47;
    *(f32x4*)&red2[row][16] = v03; *(f32x4*)&red2[row][20] = v47;
    *(f32x4*)&red2[row][24] = g03; *(f32x4*)&red2[row][28] = g47;
  }
  __syncthreads();
  if (tid < 32) {
    float s = 0.f;
    #pragma unroll
    for (int r = 0; r < 16; ++r) s += red2[r][tid];
    int mat = tid >> 3;
    if (mat == 0) s = tanhf(s);
    else if (mat == 3) s = 1.f / (1.f + expf(-s));
    lora8[(size_t)rr * 32 + tid] = s;
  }
}

// ---------------- 256x256 8-wave double-buffered MFMA GEMM (counted vmcnt) ----------------
__device__ __forceinline__ int swzslot(int row, int slot) {
  return slot ^ ((row >> 1) & 3);
}

__global__ __launch_bounds__(512)
void gemm8_k(const u16* __restrict__ A0, const u16* __restrict__ A1,
             const u16* __restrict__ A2, const u16* __restrict__ B0,
             const u16* __restrict__ B1, const u16* __restrict__ B2,
             char* __restrict__ out, int pmode) {
  extern __shared__ __attribute__((aligned(16))) char smem[];
  u16* Asm = (u16*)smem;               // [db][kh][8192] u16  (64 KB)
  u16* Bsm = (u16*)(smem + 65536);     // [db][kh][8192] u16  (64 KB)
  const int z = blockIdx.z;
  const u16* A = (z == 0) ? A0 : (z == 1) ? A1 : A2;
  const u16* Bw = (z == 0) ? B0 : (z == 1) ? B1 : B2;
  const int sbase = (z == 0) ? 4 : (z == 1) ? 6 : 192;
  const int sstr = (z == 2) ? 2 : 8;
  const int tid = threadIdx.x;
  const int wv = tid >> 6, ln = tid & 63;
  const int wr = wv >> 2, wc = wv & 3;         // 2 x 4 wave grid
  // XCD-bijective swizzle of the 8x32 tile grid (nwg=256, 256%8==0)
  const int bid = blockIdx.x + (blockIdx.y << 3);
  const int sw = (bid & 7) * 32 + (bid >> 3);
  const int row0 = (sw >> 3) * 256, col0 = (sw & 7) * 256;
  const int s_rw = tid >> 2;
  const int s_slotL = (tid & 3) ^ ((s_rw >> 1) & 3);   // logical slot fetched
  int aoff[8], boff[4];
  #pragma unroll
  for (int m = 0; m < 8; ++m) {
    int row = wr * 128 + m * 16 + (ln & 15);
    aoff[m] = row * 32 + swzslot(row, ln >> 4) * 8;
  }
  #pragma unroll
  for (int n = 0; n < 4; ++n) {
    int row = wc * 64 + n * 16 + (ln & 15);
    boff[n] = row * 32 + swzslot(row, ln >> 4) * 8;
  }
  f32x4 acc[8][4];
  #pragma unroll
  for (int m = 0; m < 8; ++m)
    #pragma unroll
    for (int n = 0; n < 4; ++n) acc[m][n] = (f32x4){0.f, 0.f, 0.f, 0.f};

  auto abase = [&](int db, int kh) -> u16* { return Asm + (db * 2 + kh) * 8192; };
  auto bbase = [&](int db, int kh) -> u16* { return Bsm + (db * 2 + kh) * 8192; };
  auto stage1 = [&](const u16* src, int baserow, u16* lbase, int kh, int skt, int rblk) {
    const u16* g = src + (size_t)(baserow + rblk * 128 + s_rw) * 2048
                   + skt * 64 + kh * 32 + s_slotL * 8;
    gld16(g, lbase + rblk * 4096 + wv * 512);
  };
  auto khblock = [&](int db, int kh, int skt, bool doStage) {
    const u16* Ab = abase(db, kh);
    const u16* Bb = bbase(db, kh);
    const int sdb = db ^ 1;
    bf16x8 bf[4], af[4];
    #pragma unroll
    for (int n = 0; n < 4; ++n) bf[n] = *(const bf16x8*)(Bb + boff[n]);
    #pragma unroll
    for (int m = 0; m < 4; ++m) af[m] = *(const bf16x8*)(Ab + aoff[m]);
    if (doStage) {
      stage1(A, row0, abase(sdb, kh), kh, skt, 0);
      stage1(A, row0, abase(sdb, kh), kh, skt, 1);
    }
    __builtin_amdgcn_s_setprio(1);
    #pragma unroll
    for (int m = 0; m < 4; ++m)
      #pragma unroll
      for (int n = 0; n < 4; ++n)
        acc[m][n] = __builtin_amdgcn_mfma_f32_16x16x32_bf16(af[m], bf[n], acc[m][n], 0, 0, 0);
    __builtin_amdgcn_s_setprio(0);
    #pragma unroll
    for (int m = 0; m < 4; ++m) af[m] = *(const bf16x8*)(Ab + aoff[4 + m]);
    if (doStage) {
      stage1(Bw, col0, bbase(sdb, kh), kh, skt, 0);
      stage1(Bw, col0, bbase(sdb, kh), kh, skt, 1);
    }
    __builtin_amdgcn_s_setprio(1);
    #pragma unroll
    for (int m = 0; m < 4; ++m)
      #pragma unroll
      for (int n = 0; n < 4; ++n)
        acc[4 + m][n] = __builtin_amdgcn_mfma_f32_16x16x32_bf16(af[m], bf[n], acc[4 + m][n], 0, 0, 0);
    __builtin_amdgcn_s_setprio(0);
  };

  stage1(A, row0, abase(0, 0), 0, 0, 0); stage1(A, row0, abase(0, 0), 0, 0, 1);
  stage1(Bw, col0, bbase(0, 0), 0, 0, 0); stage1(Bw, col0, bbase(0, 0), 0, 0, 1);
  stage1(A, row0, abase(0, 1), 1, 0, 0); stage1(A, row0, abase(0, 1), 1, 0, 1);
  stage1(Bw, col0, bbase(0, 1), 1, 0, 0); stage1(Bw, col0, bbase(0, 1), 1, 0, 1);
  asm volatile("s_waitcnt vmcnt(4)" ::: "memory");
  __builtin_amdgcn_s_barrier();
  for (int kt = 0; kt < 31; ++kt) {
    const int db = kt & 1;
    khblock(db, 0, kt + 1, true);
    asm volatile("s_waitcnt vmcnt(4)" ::: "memory");
    __builtin_amdgcn_s_barrier();
    khblock(db, 1, kt + 1, true);
    asm volatile("s_waitcnt vmcnt(4)" ::: "memory");
    __builtin_amdgcn_s_barrier();
  }
  khblock(1, 0, 0, false);
  asm volatile("s_waitcnt vmcnt(0)" ::: "memory");
  __builtin_amdgcn_s_barrier();
  khblock(1, 1, 0, false);

  const int rowb = row0 + wr * 128 + ((ln >> 4) << 2);
  const int colb = col0 + wc * 64 + (ln & 15);
  #pragma unroll
  for (int m = 0; m < 8; ++m)
    #pragma unroll
    for (int n = 0; n < 4; ++n)
      #pragma unroll
      for (int qq = 0; qq < 4; ++qq) {
        int row = rowb + m * 16 + qq;
        int col = colb + n * 16;
        float val = acc[m][n][qq];
        if (pmode == 0) {
          ((float*)out)[(size_t)row * 2048 + col] = val;
        } else {
          int bq = row >> 12, tq = row & (T_LEN - 1);
          int hq = col >> 4, jq = col & 15;
          *(u16*)(out + (size_t)((bq * 128 + hq) * T_LEN + tq) * REC
                  + sbase + jq * sstr) = f2bf(val);
        }
      }
}

// ---------------- post-GEMM: LoRA-up, decay, v-mix, kk-norm (coalesced module mapping) ----------------
// block = (t-group x, module y of 4 heads, batch z); lane = one channel.
__global__ __launch_bounds__(256)
void post_gemm_k(const float* __restrict__ v_first, const float* __restrict__ lora8,
                 const float* __restrict__ w0, const float* __restrict__ w2,
                 const float* __restrict__ a0, const float* __restrict__ a2,
                 const float* __restrict__ v0, const float* __restrict__ v2,
                 const float* __restrict__ k_k, const float* __restrict__ k_a,
                 char* __restrict__ packed) {
  const int tg = blockIdx.x;          // 0..1023 (4 t each)
  const int mo = blockIdx.y;          // module 0..31 (64 channels)
  const int bq = blockIdx.z;
  const int tid = threadIdx.x;
  const int wv = tid >> 6, ln = tid & 63;
  const int t = tg * 4 + wv;
  const int cc = ln & 15;
  const int hq = mo * 4 + (ln >> 4);
  const int c = mo * 64 + ln;
  char* pb = packed + (size_t)((bq * 128 + hq) * T_LEN + t) * REC;
  const int rr = bq * T_LEN + t;
  // word1 = [k lo16 | r hi16]; r preserved through rewrite
  u32 kr = *(const u32*)(pb + cc * 8 + 4);
  float kraw = bflo(kr);
  float vraw = bflo(*(const u16*)(pb + 192 + cc * 2));
  float vf = v_first[(size_t)rr * C_DIM + c];
  const float* lo = lora8 + (size_t)rr * 32;
  float wr_ = w0[c], ar_ = a0[c], vr_ = v0[c];
  #pragma unroll
  for (int l = 0; l < 8; ++l) {
    wr_ = fmaf(lo[l], w2[l * C_DIM + c], wr_);
    ar_ = fmaf(lo[8 + l], a2[l * C_DIM + c], ar_);
    vr_ = fmaf(lo[16 + l], v2[l * C_DIM + c], vr_);
  }
  float w_ = -log1pf(expf(-wr_)) - 0.5f;
  float dec = expf(-expf(w_));
  float a_ = 1.f / (1.f + expf(-ar_));
  float vm = 1.f / (1.f + expf(-vr_));
  float vnew = fmaf(vf - vraw, vm, vraw);
  float kk = kraw * k_k[c];
  float ss = red16(kk * kk);
  ss += __shfl_xor(ss, 16);
  ss += __shfl_xor(ss, 32);
  float sc = 1.f / fmaxf(sqrtf(ss), 1e-8f);
  float kn = kk * sc;
  u16 wa = f2bf(-kn);
  u16 wb = f2bf(kn * a_);
  u16 wk = f2bf(kraw * fmaf(a_ - 1.f, k_a[c], 1.f));
  *(u32*)(pb + cc * 8) = (u32)wa | ((u32)wb << 16);
  *(u32*)(pb + cc * 8 + 4) = (u32)wk | (kr & 0xffff0000u);
  *(u16*)(pb + 192 + cc * 2) = f2bf(vnew);
  *(float*)(pb + 128 + cc * 4) = dec;
}

// ---------------- sequential RWKV7 scan: 1 head / 4-wave block, 1 elem/lane ----------------
// r10 structure + full unroll (immediate LDS offsets) + LDS-staged y with
// coalesced per-chunk flush (no scattered global stores in the hot loop).
__device__ __forceinline__ void stage(const char* g, char* l, int wv, int ln) {
  gld16(g + wv * 1024 + ln * 16, l + wv * 1024);
  gld16(g + 4096 + wv * 1024 + ln * 16, l + 4096 + wv * 1024);
  gld16(g + 8192 + wv * 1024 + ln * 16, l + 8192 + wv * 1024);
  if (wv < 2) gld16(g + 12288 + wv * 1024 + ln * 16, l + 12288 + wv * 1024);
}

__global__ __launch_bounds__(256)
void scan_k(char* __restrict__ packed) {
  // 2 chunk halves + 1 KB pad so tail prefetch over-reads stay in-bounds
  __shared__ __attribute__((aligned(16))) char bufm[2 * CHB + 1024];
  __shared__ __attribute__((aligned(16))) float ybuf[CH * 16];
  const int hb = blockIdx.x;
  const int tid = threadIdx.x;
  const int wv = tid >> 6, ln = tid & 63;
  const int j = ln & 15;
  const int i = wv * 4 + (ln >> 4);
  char* src = packed + (size_t)hb * (T_LEN * REC);
  float S = 0.f;
  stage(src, bufm, wv, ln);
  const int NC = T_LEN / CH;
  for (int c = 0; c < NC; ++c) {
    asm volatile("s_waitcnt vmcnt(0)" ::: "memory");
    __syncthreads();
    if (c + 1 < NC)
      stage(src + (size_t)(c + 1) * CHB, bufm + ((c + 1) & 1) * CHB, wv, ln);
    const char* Bp = bufm + (c & 1) * CHB;
    const char* p0 = Bp + j * 8;         // [a|b][k|r] packet, +t*REC
    const char* pd = Bp + 128 + j * 4;   // dec f32
    const char* pv = Bp + 192 + i * 2;   // v bf16
    // preload steps 0,1
    u32x2 kA = *(const u32x2*)(p0);
    float dA = *(const float*)(pd);
    u32 vA = *(const u16*)(pv);
    u32x2 kB = *(const u32x2*)(p0 + REC);
    float dB = *(const float*)(pd + REC);
    u32 vB = *(const u16*)(pv + REC);
    #pragma unroll
    for (int t = 0; t < CH; t += 2) {
      // prefetch t+2 (over-reads land in pad, discarded at chunk restart)
      u32x2 nkA = *(const u32x2*)(p0 + (t + 2) * REC);
      float ndA = *(const float*)(pd + (t + 2) * REC);
      u32 nvA = *(const u16*)(pv + (t + 2) * REC);
      {
        float a_ = bflo(kA[0]), b_ = bfhi(kA[0]);
        float k_ = bflo(kA[1]), r_ = bfhi(kA[1]);
        float v_ = bflo(vA);
        float sa = red16(S * a_);
        S = fmaf(S, dA, fmaf(sa, b_, v_ * k_));
        float yv = red16(S * r_);
        if (j == 0) ybuf[t * 16 + i] = yv;
      }
      kA = nkA; dA = ndA; vA = nvA;
      // prefetch t+3
      u32x2 nkB = *(const u32x2*)(p0 + (t + 3) * REC);
      float ndB = *(const float*)(pd + (t + 3) * REC);
      u32 nvB = *(const u16*)(pv + (t + 3) * REC);
      {
        float a_ = bflo(kB[0]), b_ = bfhi(kB[0]);
        float k_ = bflo(kB[1]), r_ = bfhi(kB[1]);
        float v_ = bflo(vB);
        float sa = red16(S * a_);
        S = fmaf(S, dB, fmaf(sa, b_, v_ * k_));
        float yv = red16(S * r_);
        if (j == 0) ybuf[(t + 1) * 16 + i] = yv;
      }
      kB = nkB; dB = ndB; vB = nvB;
    }
    __syncthreads();
    // coalesced y flush: thread -> record tid>>2, 16B part tid&3
    {
      const int rec = tid >> 2, part = tid & 3;
      f32x4 y4 = *(const f32x4*)(ybuf + rec * 16 + part * 4);
      *(f32x4*)(src + (size_t)c * CHB + rec * REC + 128 + part * 16) = y4;
    }
  }
}

// ---------------- GroupNorm + residual + gate -> bf16 (coalesced module mapping) ----------------
// block = (batch z, module y of 4 heads, 4 consecutive t x). lane = one channel.
__global__ __launch_bounds__(256)
void post_gn_k(const char* __restrict__ packed, const float* __restrict__ lora8,
               const float* __restrict__ g2, const float* __restrict__ ln_g,
               const float* __restrict__ ln_b, const float* __restrict__ r_k,
               u16* __restrict__ og) {
  const int tg = blockIdx.x;          // 0..1023 (4 t each)
  const int mo = blockIdx.y;          // module 0..31 (64 channels)
  const int bq = blockIdx.z;
  const int tid = threadIdx.x;
  const int wv = tid >> 6, ln = tid & 63;
  const int t = tg * 4 + wv;
  const int cc = ln & 15;
  const int hq = mo * 4 + (ln >> 4);
  const int c = mo * 64 + ln;
  const char* pb = packed + (size_t)((bq * 128 + hq) * T_LEN + t) * REC;
  u32 kr = *(const u32*)(pb + cc * 8 + 4);
  float kv = bflo(kr), rv = bfhi(kr);
  float vv = bflo(*(const u16*)(pb + 192 + cc * 2));
  float o = *(const float*)(pb + 128 + cc * 4);
  const int rr = bq * T_LEN + t;
  const float* lo = lora8 + (size_t)rr * 32 + 24;
  float gg = 0.f;
  #pragma unroll
  for (int l = 0; l < 8; ++l) gg = fmaf(lo[l], g2[l * C_DIM + c], gg);
  float s1 = red16(o);
  float s2 = red16(o * o);
  float srk = red16(rv * kv * r_k[c]);
  s1 += __shfl_xor(s1, 16); s2 += __shfl_xor(s2, 16); srk += __shfl_xor(srk, 16);
  s1 += __shfl_xor(s1, 32); s2 += __shfl_xor(s2, 32); srk += __shfl_xor(srk, 32);
  float mu = s1 * (1.f / 64.f);
  float var = s2 * (1.f / 64.f) - mu * mu;
  float rstd = rsqrtf(var + 0.00064f);
  float on = fmaf((o - mu) * rstd, ln_g[c], ln_b[c]);
  float o2 = fmaf(srk, vv, on);
  og[(size_t)rr * C_DIM + c] = f2bf(o2 * gg);
}

extern "C" void kernel_launch(void* const* d_in, const int* in_sizes, int n_in,
                              void* d_out, int out_size, void* d_ws, size_t ws_size,
                              hipStream_t stream) {
  (void)in_sizes; (void)n_in; (void)out_size;
  const float* x      = (const float*)d_in[0];
  const float* v_first= (const float*)d_in[1];
  const float* x_r    = (const float*)d_in[2];
  const float* x_w    = (const float*)d_in[3];
  const float* x_k    = (const float*)d_in[4];
  const float* x_v    = (const float*)d_in[5];
  const float* x_a    = (const float*)d_in[6];
  const float* x_g    = (const float*)d_in[7];
  const float* w0     = (const float*)d_in[8];
  const float* w1     = (const float*)d_in[9];
  const float* w2     = (const float*)d_in[10];
  const float* a0     = (const float*)d_in[11];
  const float* a1     = (const float*)d_in[12];
  const float* a2     = (const float*)d_in[13];
  const float* v0     = (const float*)d_in[14];
  const float* v1     = (const float*)d_in[15];
  const float* v2     = (const float*)d_in[16];
  const float* g1     = (const float*)d_in[17];
  const float* g2     = (const float*)d_in[18];
  const float* k_k    = (const float*)d_in[19];
  const float* k_a    = (const float*)d_in[20];
  const float* r_k    = (const float*)d_in[21];
  const float* Wr     = (const float*)d_in[22];
  const float* Wk     = (const float*)d_in[23];
  const float* Wv     = (const float*)d_in[24];
  const float* Wo     = (const float*)d_in[25];
  const float* ln_g   = (const float*)d_in[26];
  const float* ln_b   = (const float*)d_in[27];

  if (ws_size < 370147328ull) return;
  char* ws = (char*)d_ws;
  u16* Wr_bf = (u16*)(ws + 0);            //  8 MB each, contiguous (conv indexes)
  u16* Wk_bf = Wr_bf + 4194304;
  u16* Wv_bf = Wk_bf + 4194304;
  u16* Wo_bf = Wv_bf + 4194304;
  u16* xr_bf = (u16*)(ws + 33554432);     // 32 MB each
  u16* xk_bf = xr_bf + 16777216;
  u16* xv_bf = xk_bf + 16777216;
  float* lora8 = (float*)(ws + 134217728); // 1 MB
  char* packed = ws + 135266304;           // 224 MB
  float* wt = (float*)packed;              // transposed LoRA tables (256 KB),
                                           // consumed before gemms overwrite
  u16* og = xr_bf;                         // reuse (dead after r-GEMM)
  float* out = (float*)d_out;

  (void)hipFuncSetAttribute((const void*)gemm8_k,
                            hipFuncAttributeMaxDynamicSharedMemorySize, 131072);

  conv_bf16_k<<<dim3(2048, 4), 256, 0, stream>>>(Wr, Wk, Wv, Wo, Wr_bf);
  trans_lora_k<<<dim3(8, 4), 256, 0, stream>>>(w1, a1, v1, g1, wt);

  mix_lora_k<<<8192, 256, 0, stream>>>(x, x_r, x_w, x_k, x_v, x_a, x_g,
                                       wt, xr_bf, xk_bf, xv_bf, lora8);

  gemm8_k<<<dim3(8, 32, 3), 512, 131072, stream>>>(xk_bf, xr_bf, xv_bf,
                                                   Wk_bf, Wr_bf, Wv_bf,
                                                   packed, 1);

  post_gemm_k<<<dim3(1024, 32, 2), 256, 0, stream>>>(v_first, lora8, w0, w2,
                                                     a0, a2, v0, v2,
                                                     k_k, k_a, packed);

  scan_k<<<256, 256, 0, stream>>>(packed);

  post_gn_k<<<dim3(1024, 32, 2), 256, 0, stream>>>(packed, lora8, g2,
                                                   ln_g, ln_b, r_k, og);

  gemm8_k<<<dim3(8, 32, 1), 512, 131072, stream>>>(og, og, og,
                                                   Wo_bf, Wo_bf, Wo_bf,
                                                   (char*)out, 0);

  hipMemcpyAsync(out + 16777216, v_first, (size_t)16777216 * 4,
                 hipMemcpyDeviceToDevice, stream);
}

// Round 15
// 1186.585 us; speedup vs baseline: 1.1784x; 1.0565x over previous
//
#include <hip/hip_runtime.h>

#define T_LEN 4096
#define C_DIM 2048
#define REC 224          // packed record: 16x[a,b,k,r] bf16 128B | dec/y f32 64B | v bf16 32B
#define CH 64            // scan steps per LDS chunk (64*224 = 14336 B)
#define CHB (CH * REC)

typedef __attribute__((ext_vector_type(4))) float f32x4;
typedef __attribute__((ext_vector_type(8))) __bf16 bf16x8;
typedef __attribute__((ext_vector_type(8))) unsigned short u16x8;
typedef __attribute__((ext_vector_type(4))) unsigned int u32x4;
typedef __attribute__((ext_vector_type(2))) unsigned int u32x2;
typedef unsigned short u16;
typedef unsigned int u32;

typedef __attribute__((address_space(1))) const void* as1cv;
typedef __attribute__((address_space(3))) void* as3v;

__device__ __forceinline__ void gld16(const void* g, void* l) {
  __builtin_amdgcn_global_load_lds((as1cv)g, (as3v)l, 16, 0, 0);
}

__device__ __forceinline__ u16 f2bf(float f) {
  union { float f; unsigned u; } x; x.f = f;
  return (u16)((x.u + 0x7fffu + ((x.u >> 16) & 1u)) >> 16);
}
__device__ __forceinline__ float bflo(unsigned u) {
  union { unsigned u; float f; } x; x.u = u << 16; return x.f;
}
__device__ __forceinline__ float bfhi(unsigned u) {
  union { unsigned u; float f; } x; x.u = u & 0xffff0000u; return x.f;
}
// sum over a 16-lane row via DPP (xor1, xor2, row_ror:4, row_ror:8) — all lanes get the sum
__device__ __forceinline__ float red16(float x) {
  int a;
  a = __builtin_amdgcn_update_dpp(0, __builtin_bit_cast(int, x), 0xB1, 0xF, 0xF, true);
  x += __builtin_bit_cast(float, a);
  a = __builtin_amdgcn_update_dpp(0, __builtin_bit_cast(int, x), 0x4E, 0xF, 0xF, true);
  x += __builtin_bit_cast(float, a);
  a = __builtin_amdgcn_update_dpp(0, __builtin_bit_cast(int, x), 0x124, 0xF, 0xF, true);
  x += __builtin_bit_cast(float, a);
  a = __builtin_amdgcn_update_dpp(0, __builtin_bit_cast(int, x), 0x128, 0xF, 0xF, true);
  x += __builtin_bit_cast(float, a);
  return x;
}
__device__ __forceinline__ f32x4 red16v(f32x4 v) {
  v[0] = red16(v[0]); v[1] = red16(v[1]);
  v[2] = red16(v[2]); v[3] = red16(v[3]);
  return v;
}

// ---------------- weights fp32 -> bf16 (all four in one launch) ----------------
__global__ __launch_bounds__(256)
void conv_bf16_k(const float* __restrict__ s0, const float* __restrict__ s1,
                 const float* __restrict__ s2, const float* __restrict__ s3,
                 u16* __restrict__ d0) {
  const float* s = (blockIdx.y == 0) ? s0 : (blockIdx.y == 1) ? s1
                   : (blockIdx.y == 2) ? s2 : s3;
  u16* d = d0 + (size_t)blockIdx.y * 4194304;
  int i = (blockIdx.x * 256 + threadIdx.x) * 8;
  f32x4 a = *(const f32x4*)(s + i);
  f32x4 b = *(const f32x4*)(s + i + 4);
  u16x8 o;
  o[0] = f2bf(a[0]); o[1] = f2bf(a[1]); o[2] = f2bf(a[2]); o[3] = f2bf(a[3]);
  o[4] = f2bf(b[0]); o[5] = f2bf(b[1]); o[6] = f2bf(b[2]); o[7] = f2bf(b[3]);
  *(u16x8*)(d + i) = o;
}

// ---------------- LoRA-down matrices: (C x 8) -> (8 x C) fp32 transpose ----------------
__global__ __launch_bounds__(256)
void trans_lora_k(const float* __restrict__ w1, const float* __restrict__ a1,
                  const float* __restrict__ v1, const float* __restrict__ g1,
                  float* __restrict__ wt) {
  const float* s = (blockIdx.y == 0) ? w1 : (blockIdx.y == 1) ? a1
                   : (blockIdx.y == 2) ? v1 : g1;
  float* d = wt + (size_t)blockIdx.y * (8 * C_DIM);
  int c = blockIdx.x * 256 + threadIdx.x;    // grid.x = 8
  f32x4 lo = *(const f32x4*)(s + c * 8);
  f32x4 hi = *(const f32x4*)(s + c * 8 + 4);
  d[0 * C_DIM + c] = lo[0]; d[1 * C_DIM + c] = lo[1];
  d[2 * C_DIM + c] = lo[2]; d[3 * C_DIM + c] = lo[3];
  d[4 * C_DIM + c] = hi[0]; d[5 * C_DIM + c] = hi[1];
  d[6 * C_DIM + c] = hi[2]; d[7 * C_DIM + c] = hi[3];
}

// ---------------- mix + LoRA down (strided mapping, all loads coalesced) ----------------
__global__ __launch_bounds__(256)
void mix_lora_k(const float* __restrict__ x,
                const float* __restrict__ xrw, const float* __restrict__ xww,
                const float* __restrict__ xkw, const float* __restrict__ xvw,
                const float* __restrict__ xaw, const float* __restrict__ xgw,
                const float* __restrict__ wt,   // 4 transposed tables, 8xC each
                u16* __restrict__ xr_bf, u16* __restrict__ xk_bf,
                u16* __restrict__ xv_bf, float* __restrict__ lora8) {
  const int rr = blockIdx.x;
  const int t = rr & (T_LEN - 1);
  const int tid = threadIdx.x;
  const float* xrow = x + (size_t)rr * C_DIM;
  float wl[8], al[8], vl[8], gl[8];
  #pragma unroll
  for (int l = 0; l < 8; ++l) { wl[l] = 0.f; al[l] = 0.f; vl[l] = 0.f; gl[l] = 0.f; }
  #pragma unroll
  for (int ii = 0; ii < 8; ++ii) {
    const int c = ii * 256 + tid;
    float xi = xrow[c];
    float xpv = t ? xrow[c - C_DIM] : 0.f;
    float dx = xpv - xi;
    float xr_ = fmaf(dx, xrw[c], xi);
    float xw_ = fmaf(dx, xww[c], xi);
    float xk_ = fmaf(dx, xkw[c], xi);
    float xv_ = fmaf(dx, xvw[c], xi);
    float xa_ = fmaf(dx, xaw[c], xi);
    float xg_ = fmaf(dx, xgw[c], xi);
    xr_bf[(size_t)rr * C_DIM + c] = f2bf(xr_);
    xk_bf[(size_t)rr * C_DIM + c] = f2bf(xk_);
    xv_bf[(size_t)rr * C_DIM + c] = f2bf(xv_);
    #pragma unroll
    for (int l = 0; l < 8; ++l) {
      wl[l] = fmaf(xw_, wt[l * C_DIM + c], wl[l]);
      al[l] = fmaf(xa_, wt[16384 + l * C_DIM + c], al[l]);
      vl[l] = fmaf(xv_, wt[32768 + l * C_DIM + c], vl[l]);
      gl[l] = fmaf(xg_, wt[49152 + l * C_DIM + c], gl[l]);
    }
  }
  // row-reduce (16 lanes) all 32 partials via DPP — pure VALU
  f32x4 w03 = red16v((f32x4){wl[0], wl[1], wl[2], wl[3]});
  f32x4 w47 = red16v((f32x4){wl[4], wl[5], wl[6], wl[7]});
  f32x4 a03 = red16v((f32x4){al[0], al[1], al[2], al[3]});
  f32x4 a47 = red16v((f32x4){al[4], al[5], al[6], al[7]});
  f32x4 v03 = red16v((f32x4){vl[0], vl[1], vl[2], vl[3]});
  f32x4 v47 = red16v((f32x4){vl[4], vl[5], vl[6], vl[7]});
  f32x4 g03 = red16v((f32x4){gl[0], gl[1], gl[2], gl[3]});
  f32x4 g47 = red16v((f32x4){gl[4], gl[5], gl[6], gl[7]});
  __shared__ __attribute__((aligned(16))) float red2[16][32];
  const int row = tid >> 4;          // 16 rows of 16 lanes
  if ((tid & 15) == 0) {
    *(f32x4*)&red2[row][0] = w03;  *(f32x4*)&red2[row][4] = w47;
    *(f32x4*)&red2[row][8] = a03;  *(f32x4*)&red2[row][12] = a47;
    *(f32x4*)&red2[row][16] = v03; *(f32x4*)&red2[row][20] = v47;
    *(f32x4*)&red2[row][24] = g03; *(f32x4*)&red2[row][28] = g47;
  }
  __syncthreads();
  if (tid < 32) {
    float s = 0.f;
    #pragma unroll
    for (int r = 0; r < 16; ++r) s += red2[r][tid];
    int mat = tid >> 3;
    if (mat == 0) s = tanhf(s);
    else if (mat == 3) s = 1.f / (1.f + expf(-s));
    lora8[(size_t)rr * 32 + tid] = s;
  }
}

// ---------------- 256x256 8-wave double-buffered MFMA GEMM (counted vmcnt) ----------------
__device__ __forceinline__ int swzslot(int row, int slot) {
  return slot ^ ((row >> 1) & 3);
}

__global__ __launch_bounds__(512)
void gemm8_k(const u16* __restrict__ A0, const u16* __restrict__ A1,
             const u16* __restrict__ A2, const u16* __restrict__ B0,
             const u16* __restrict__ B1, const u16* __restrict__ B2,
             char* __restrict__ out, int pmode) {
  extern __shared__ __attribute__((aligned(16))) char smem[];
  u16* Asm = (u16*)smem;               // [db][kh][8192] u16  (64 KB)
  u16* Bsm = (u16*)(smem + 65536);     // [db][kh][8192] u16  (64 KB)
  const int z = blockIdx.z;
  const u16* A = (z == 0) ? A0 : (z == 1) ? A1 : A2;
  const u16* Bw = (z == 0) ? B0 : (z == 1) ? B1 : B2;
  const int sbase = (z == 0) ? 4 : (z == 1) ? 6 : 192;
  const int sstr = (z == 2) ? 2 : 8;
  const int tid = threadIdx.x;
  const int wv = tid >> 6, ln = tid & 63;
  const int wr = wv >> 2, wc = wv & 3;         // 2 x 4 wave grid
  // XCD-bijective swizzle of the 8x32 tile grid (nwg=256, 256%8==0)
  const int bid = blockIdx.x + (blockIdx.y << 3);
  const int sw = (bid & 7) * 32 + (bid >> 3);
  const int row0 = (sw >> 3) * 256, col0 = (sw & 7) * 256;
  const int s_rw = tid >> 2;
  const int s_slotL = (tid & 3) ^ ((s_rw >> 1) & 3);   // logical slot fetched
  int aoff[8], boff[4];
  #pragma unroll
  for (int m = 0; m < 8; ++m) {
    int row = wr * 128 + m * 16 + (ln & 15);
    aoff[m] = row * 32 + swzslot(row, ln >> 4) * 8;
  }
  #pragma unroll
  for (int n = 0; n < 4; ++n) {
    int row = wc * 64 + n * 16 + (ln & 15);
    boff[n] = row * 32 + swzslot(row, ln >> 4) * 8;
  }
  f32x4 acc[8][4];
  #pragma unroll
  for (int m = 0; m < 8; ++m)
    #pragma unroll
    for (int n = 0; n < 4; ++n) acc[m][n] = (f32x4){0.f, 0.f, 0.f, 0.f};

  auto abase = [&](int db, int kh) -> u16* { return Asm + (db * 2 + kh) * 8192; };
  auto bbase = [&](int db, int kh) -> u16* { return Bsm + (db * 2 + kh) * 8192; };
  auto stage1 = [&](const u16* src, int baserow, u16* lbase, int kh, int skt, int rblk) {
    const u16* g = src + (size_t)(baserow + rblk * 128 + s_rw) * 2048
                   + skt * 64 + kh * 32 + s_slotL * 8;
    gld16(g, lbase + rblk * 4096 + wv * 512);
  };
  auto khblock = [&](int db, int kh, int skt, bool doStage) {
    const u16* Ab = abase(db, kh);
    const u16* Bb = bbase(db, kh);
    const int sdb = db ^ 1;
    bf16x8 bf[4], af[4];
    #pragma unroll
    for (int n = 0; n < 4; ++n) bf[n] = *(const bf16x8*)(Bb + boff[n]);
    #pragma unroll
    for (int m = 0; m < 4; ++m) af[m] = *(const bf16x8*)(Ab + aoff[m]);
    if (doStage) {
      stage1(A, row0, abase(sdb, kh), kh, skt, 0);
      stage1(A, row0, abase(sdb, kh), kh, skt, 1);
    }
    __builtin_amdgcn_s_setprio(1);
    #pragma unroll
    for (int m = 0; m < 4; ++m)
      #pragma unroll
      for (int n = 0; n < 4; ++n)
        acc[m][n] = __builtin_amdgcn_mfma_f32_16x16x32_bf16(af[m], bf[n], acc[m][n], 0, 0, 0);
    __builtin_amdgcn_s_setprio(0);
    #pragma unroll
    for (int m = 0; m < 4; ++m) af[m] = *(const bf16x8*)(Ab + aoff[4 + m]);
    if (doStage) {
      stage1(Bw, col0, bbase(sdb, kh), kh, skt, 0);
      stage1(Bw, col0, bbase(sdb, kh), kh, skt, 1);
    }
    __builtin_amdgcn_s_setprio(1);
    #pragma unroll
    for (int m = 0; m < 4; ++m)
      #pragma unroll
      for (int n = 0; n < 4; ++n)
        acc[4 + m][n] = __builtin_amdgcn_mfma_f32_16x16x32_bf16(af[m], bf[n], acc[4 + m][n], 0, 0, 0);
    __builtin_amdgcn_s_setprio(0);
  };

  stage1(A, row0, abase(0, 0), 0, 0, 0); stage1(A, row0, abase(0, 0), 0, 0, 1);
  stage1(Bw, col0, bbase(0, 0), 0, 0, 0); stage1(Bw, col0, bbase(0, 0), 0, 0, 1);
  stage1(A, row0, abase(0, 1), 1, 0, 0); stage1(A, row0, abase(0, 1), 1, 0, 1);
  stage1(Bw, col0, bbase(0, 1), 1, 0, 0); stage1(Bw, col0, bbase(0, 1), 1, 0, 1);
  asm volatile("s_waitcnt vmcnt(4)" ::: "memory");
  __builtin_amdgcn_s_barrier();
  for (int kt = 0; kt < 31; ++kt) {
    const int db = kt & 1;
    khblock(db, 0, kt + 1, true);
    asm volatile("s_waitcnt vmcnt(4)" ::: "memory");
    __builtin_amdgcn_s_barrier();
    khblock(db, 1, kt + 1, true);
    asm volatile("s_waitcnt vmcnt(4)" ::: "memory");
    __builtin_amdgcn_s_barrier();
  }
  khblock(1, 0, 0, false);
  asm volatile("s_waitcnt vmcnt(0)" ::: "memory");
  __builtin_amdgcn_s_barrier();
  khblock(1, 1, 0, false);

  const int rowb = row0 + wr * 128 + ((ln >> 4) << 2);
  const int colb = col0 + wc * 64 + (ln & 15);
  #pragma unroll
  for (int m = 0; m < 8; ++m)
    #pragma unroll
    for (int n = 0; n < 4; ++n)
      #pragma unroll
      for (int qq = 0; qq < 4; ++qq) {
        int row = rowb + m * 16 + qq;
        int col = colb + n * 16;
        float val = acc[m][n][qq];
        if (pmode == 0) {
          ((float*)out)[(size_t)row * 2048 + col] = val;
        } else {
          int bq = row >> 12, tq = row & (T_LEN - 1);
          int hq = col >> 4, jq = col & 15;
          *(u16*)(out + (size_t)((bq * 128 + hq) * T_LEN + tq) * REC
                  + sbase + jq * sstr) = f2bf(val);
        }
      }
}

// ---------------- post-GEMM: LoRA-up, decay, v-mix, kk-norm (coalesced module mapping) ----------------
// block = (t-group x, module y of 4 heads, batch z); lane = one channel.
__global__ __launch_bounds__(256)
void post_gemm_k(const float* __restrict__ v_first, const float* __restrict__ lora8,
                 const float* __restrict__ w0, const float* __restrict__ w2,
                 const float* __restrict__ a0, const float* __restrict__ a2,
                 const float* __restrict__ v0, const float* __restrict__ v2,
                 const float* __restrict__ k_k, const float* __restrict__ k_a,
                 char* __restrict__ packed) {
  const int tg = blockIdx.x;          // 0..1023 (4 t each)
  const int mo = blockIdx.y;          // module 0..31 (64 channels)
  const int bq = blockIdx.z;
  const int tid = threadIdx.x;
  const int wv = tid >> 6, ln = tid & 63;
  const int t = tg * 4 + wv;
  const int cc = ln & 15;
  const int hq = mo * 4 + (ln >> 4);
  const int c = mo * 64 + ln;
  char* pb = packed + (size_t)((bq * 128 + hq) * T_LEN + t) * REC;
  const int rr = bq * T_LEN + t;
  // word1 = [k lo16 | r hi16]; r preserved through rewrite
  u32 kr = *(const u32*)(pb + cc * 8 + 4);
  float kraw = bflo(kr);
  float vraw = bflo(*(const u16*)(pb + 192 + cc * 2));
  float vf = v_first[(size_t)rr * C_DIM + c];
  const float* lo = lora8 + (size_t)rr * 32;
  float wr_ = w0[c], ar_ = a0[c], vr_ = v0[c];
  #pragma unroll
  for (int l = 0; l < 8; ++l) {
    wr_ = fmaf(lo[l], w2[l * C_DIM + c], wr_);
    ar_ = fmaf(lo[8 + l], a2[l * C_DIM + c], ar_);
    vr_ = fmaf(lo[16 + l], v2[l * C_DIM + c], vr_);
  }
  float w_ = -log1pf(expf(-wr_)) - 0.5f;
  float dec = expf(-expf(w_));
  float a_ = 1.f / (1.f + expf(-ar_));
  float vm = 1.f / (1.f + expf(-vr_));
  float vnew = fmaf(vf - vraw, vm, vraw);
  float kk = kraw * k_k[c];
  float ss = red16(kk * kk);
  ss += __shfl_xor(ss, 16);
  ss += __shfl_xor(ss, 32);
  float sc = 1.f / fmaxf(sqrtf(ss), 1e-8f);
  float kn = kk * sc;
  u16 wa = f2bf(-kn);
  u16 wb = f2bf(kn * a_);
  u16 wk = f2bf(kraw * fmaf(a_ - 1.f, k_a[c], 1.f));
  *(u32*)(pb + cc * 8) = (u32)wa | ((u32)wb << 16);
  *(u32*)(pb + cc * 8 + 4) = (u32)wk | (kr & 0xffff0000u);
  *(u16*)(pb + 192 + cc * 2) = f2bf(vnew);
  *(float*)(pb + 128 + cc * 4) = dec;
}

// ---------------- sequential RWKV7 scan: 1 head / 4-wave block, 1 elem/lane ----------------
// Distance-4 register pipeline; NO LDS ops for y in the hot loop (predicated
// register accumulation, lane j owns steps t%16==j); per-chunk ybuf dump +
// coalesced f32x4 flush.
__device__ __forceinline__ void stage(const char* g, char* l, int wv, int ln) {
  gld16(g + wv * 1024 + ln * 16, l + wv * 1024);
  gld16(g + 4096 + wv * 1024 + ln * 16, l + 4096 + wv * 1024);
  gld16(g + 8192 + wv * 1024 + ln * 16, l + 8192 + wv * 1024);
  if (wv < 2) gld16(g + 12288 + wv * 1024 + ln * 16, l + 12288 + wv * 1024);
}

__global__ __launch_bounds__(256)
void scan_k(char* __restrict__ packed) {
  // 2 chunk halves + 1 KB pad so distance-4 over-reads stay in-bounds
  __shared__ __attribute__((aligned(16))) char bufm[2 * CHB + 1024];
  __shared__ __attribute__((aligned(16))) float ybuf[CH * 16];
  const int hb = blockIdx.x;
  const int tid = threadIdx.x;
  const int wv = tid >> 6, ln = tid & 63;
  const int j = ln & 15;
  const int i = wv * 4 + (ln >> 4);
  char* src = packed + (size_t)hb * (T_LEN * REC);
  float S = 0.f;
  stage(src, bufm, wv, ln);
  const int NC = T_LEN / CH;
  for (int c = 0; c < NC; ++c) {
    asm volatile("s_waitcnt vmcnt(0)" ::: "memory");
    __syncthreads();
    if (c + 1 < NC)
      stage(src + (size_t)(c + 1) * CHB, bufm + ((c + 1) & 1) * CHB, wv, ln);
    const char* Bp = bufm + (c & 1) * CHB;
    const char* p0 = Bp + j * 8;         // [a|b][k|r] packet, +t*REC
    const char* pd = Bp + 128 + j * 4;   // dec f32
    const char* pv = Bp + 192 + i * 2;   // v bf16
    // preload steps 0..3
    u32x2 kq[4]; float dq[4]; u32 vq[4];
    #pragma unroll
    for (int s = 0; s < 4; ++s) {
      kq[s] = *(const u32x2*)(p0 + s * REC);
      dq[s] = *(const float*)(pd + s * REC);
      vq[s] = *(const u16*)(pv + s * REC);
    }
    float yq0 = 0.f, yq1 = 0.f, yq2 = 0.f, yq3 = 0.f;
    #pragma unroll
    for (int t = 0; t < CH; ++t) {
      const int st = t & 3;
      u32x2 kc = kq[st]; float dc = dq[st]; u32 vc = vq[st];
      // prefetch t+4 (tail over-reads land in pad; re-preloaded next chunk)
      kq[st] = *(const u32x2*)(p0 + (t + 4) * REC);
      dq[st] = *(const float*)(pd + (t + 4) * REC);
      vq[st] = *(const u16*)(pv + (t + 4) * REC);
      float a_ = bflo(kc[0]), b_ = bfhi(kc[0]);
      float k_ = bflo(kc[1]), r_ = bfhi(kc[1]);
      float v_ = bflo(vc);
      float sa = red16(S * a_);
      S = fmaf(S, dc, fmaf(sa, b_, v_ * k_));
      float yv = red16(S * r_);
      const bool own = (j == (t & 15));
      if ((t >> 4) == 0)      yq0 = own ? yv : yq0;
      else if ((t >> 4) == 1) yq1 = own ? yv : yq1;
      else if ((t >> 4) == 2) yq2 = own ? yv : yq2;
      else                    yq3 = own ? yv : yq3;
    }
    // dump register y to ybuf: value yqQ holds y for (t = Q*16 + j, row i)
    ybuf[(0 * 16 + j) * 16 + i] = yq0;
    ybuf[(1 * 16 + j) * 16 + i] = yq1;
    ybuf[(2 * 16 + j) * 16 + i] = yq2;
    ybuf[(3 * 16 + j) * 16 + i] = yq3;
    __syncthreads();
    // coalesced y flush: thread -> record tid>>2, 16B part tid&3
    {
      const int rec = tid >> 2, part = tid & 3;
      f32x4 y4 = *(const f32x4*)(ybuf + rec * 16 + part * 4);
      *(f32x4*)(src + (size_t)c * CHB + rec * REC + 128 + part * 16) = y4;
    }
  }
}

// ---------------- GroupNorm + residual + gate -> bf16 (coalesced module mapping) ----------------
// block = (batch z, module y of 4 heads, 4 consecutive t x). lane = one channel.
__global__ __launch_bounds__(256)
void post_gn_k(const char* __restrict__ packed, const float* __restrict__ lora8,
               const float* __restrict__ g2, const float* __restrict__ ln_g,
               const float* __restrict__ ln_b, const float* __restrict__ r_k,
               u16* __restrict__ og) {
  const int tg = blockIdx.x;          // 0..1023 (4 t each)
  const int mo = blockIdx.y;          // module 0..31 (64 channels)
  const int bq = blockIdx.z;
  const int tid = threadIdx.x;
  const int wv = tid >> 6, ln = tid & 63;
  const int t = tg * 4 + wv;
  const int cc = ln & 15;
  const int hq = mo * 4 + (ln >> 4);
  const int c = mo * 64 + ln;
  const char* pb = packed + (size_t)((bq * 128 + hq) * T_LEN + t) * REC;
  u32 kr = *(const u32*)(pb + cc * 8 + 4);
  float kv = bflo(kr), rv = bfhi(kr);
  float vv = bflo(*(const u16*)(pb + 192 + cc * 2));
  float o = *(const float*)(pb + 128 + cc * 4);
  const int rr = bq * T_LEN + t;
  const float* lo = lora8 + (size_t)rr * 32 + 24;
  float gg = 0.f;
  #pragma unroll
  for (int l = 0; l < 8; ++l) gg = fmaf(lo[l], g2[l * C_DIM + c], gg);
  float s1 = red16(o);
  float s2 = red16(o * o);
  float srk = red16(rv * kv * r_k[c]);
  s1 += __shfl_xor(s1, 16); s2 += __shfl_xor(s2, 16); srk += __shfl_xor(srk, 16);
  s1 += __shfl_xor(s1, 32); s2 += __shfl_xor(s2, 32); srk += __shfl_xor(srk, 32);
  float mu = s1 * (1.f / 64.f);
  float var = s2 * (1.f / 64.f) - mu * mu;
  float rstd = rsqrtf(var + 0.00064f);
  float on = fmaf((o - mu) * rstd, ln_g[c], ln_b[c]);
  float o2 = fmaf(srk, vv, on);
  og[(size_t)rr * C_DIM + c] = f2bf(o2 * gg);
}

extern "C" void kernel_launch(void* const* d_in, const int* in_sizes, int n_in,
                              void* d_out, int out_size, void* d_ws, size_t ws_size,
                              hipStream_t stream) {
  (void)in_sizes; (void)n_in; (void)out_size;
  const float* x      = (const float*)d_in[0];
  const float* v_first= (const float*)d_in[1];
  const float* x_r    = (const float*)d_in[2];
  const float* x_w    = (const float*)d_in[3];
  const float* x_k    = (const float*)d_in[4];
  const float* x_v    = (const float*)d_in[5];
  const float* x_a    = (const float*)d_in[6];
  const float* x_g    = (const float*)d_in[7];
  const float* w0     = (const float*)d_in[8];
  const float* w1     = (const float*)d_in[9];
  const float* w2     = (const float*)d_in[10];
  const float* a0     = (const float*)d_in[11];
  const float* a1     = (const float*)d_in[12];
  const float* a2     = (const float*)d_in[13];
  const float* v0     = (const float*)d_in[14];
  const float* v1     = (const float*)d_in[15];
  const float* v2     = (const float*)d_in[16];
  const float* g1     = (const float*)d_in[17];
  const float* g2     = (const float*)d_in[18];
  const float* k_k    = (const float*)d_in[19];
  const float* k_a    = (const float*)d_in[20];
  const float* r_k    = (const float*)d_in[21];
  const float* Wr     = (const float*)d_in[22];
  const float* Wk     = (const float*)d_in[23];
  const float* Wv     = (const float*)d_in[24];
  const float* Wo     = (const float*)d_in[25];
  const float* ln_g   = (const float*)d_in[26];
  const float* ln_b   = (const float*)d_in[27];

  if (ws_size < 370147328ull) return;
  char* ws = (char*)d_ws;
  u16* Wr_bf = (u16*)(ws + 0);            //  8 MB each, contiguous (conv indexes)
  u16* Wk_bf = Wr_bf + 4194304;
  u16* Wv_bf = Wk_bf + 4194304;
  u16* Wo_bf = Wv_bf + 4194304;
  u16* xr_bf = (u16*)(ws + 33554432);     // 32 MB each
  u16* xk_bf = xr_bf + 16777216;
  u16* xv_bf = xk_bf + 16777216;
  float* lora8 = (float*)(ws + 134217728); // 1 MB
  char* packed = ws + 135266304;           // 224 MB
  float* wt = (float*)packed;              // transposed LoRA tables (256 KB),
                                           // consumed before gemms overwrite
  u16* og = xr_bf;                         // reuse (dead after r-GEMM)
  float* out = (float*)d_out;

  (void)hipFuncSetAttribute((const void*)gemm8_k,
                            hipFuncAttributeMaxDynamicSharedMemorySize, 131072);

  conv_bf16_k<<<dim3(2048, 4), 256, 0, stream>>>(Wr, Wk, Wv, Wo, Wr_bf);
  trans_lora_k<<<dim3(8, 4), 256, 0, stream>>>(w1, a1, v1, g1, wt);

  mix_lora_k<<<8192, 256, 0, stream>>>(x, x_r, x_w, x_k, x_v, x_a, x_g,
                                       wt, xr_bf, xk_bf, xv_bf, lora8);

  gemm8_k<<<dim3(8, 32, 3), 512, 131072, stream>>>(xk_bf, xr_bf, xv_bf,
                                                   Wk_bf, Wr_bf, Wv_bf,
                                                   packed, 1);

  post_gemm_k<<<dim3(1024, 32, 2), 256, 0, stream>>>(v_first, lora8, w0, w2,
                                                     a0, a2, v0, v2,
                                                     k_k, k_a, packed);

  scan_k<<<256, 256, 0, stream>>>(packed);

  post_gn_k<<<dim3(1024, 32, 2), 256, 0, stream>>>(packed, lora8, g2,
                                                   ln_g, ln_b, r_k, og);

  gemm8_k<<<dim3(8, 32, 1), 512, 131072, stream>>>(og, og, og,
                                                   Wo_bf, Wo_bf, Wo_bf,
                                                   (char*)out, 0);

  hipMemcpyAsync(out + 16777216, v_first, (size_t)16777216 * 4,
                 hipMemcpyDeviceToDevice, stream);
}

// Round 16
// 1129.254 us; speedup vs baseline: 1.2382x; 1.0508x over previous
//
#include <hip/hip_runtime.h>

#define T_LEN 4096
#define C_DIM 2048
#define REC 224          // packed record: 16x[a,b,k,r] bf16 128B | dec/y f32 64B | v bf16 32B
#define CH 64            // scan steps per LDS chunk (64*224 = 14336 B)
#define CHB (CH * REC)

typedef __attribute__((ext_vector_type(4))) float f32x4;
typedef __attribute__((ext_vector_type(8))) __bf16 bf16x8;
typedef __attribute__((ext_vector_type(8))) unsigned short u16x8;
typedef __attribute__((ext_vector_type(4))) unsigned int u32x4;
typedef __attribute__((ext_vector_type(2))) unsigned int u32x2;
typedef unsigned short u16;
typedef unsigned int u32;

typedef __attribute__((address_space(1))) const void* as1cv;
typedef __attribute__((address_space(3))) void* as3v;

__device__ __forceinline__ void gld16(const void* g, void* l) {
  __builtin_amdgcn_global_load_lds((as1cv)g, (as3v)l, 16, 0, 0);
}

__device__ __forceinline__ u16 f2bf(float f) {
  union { float f; unsigned u; } x; x.f = f;
  return (u16)((x.u + 0x7fffu + ((x.u >> 16) & 1u)) >> 16);
}
__device__ __forceinline__ float bflo(unsigned u) {
  union { unsigned u; float f; } x; x.u = u << 16; return x.f;
}
__device__ __forceinline__ float bfhi(unsigned u) {
  union { unsigned u; float f; } x; x.u = u & 0xffff0000u; return x.f;
}
// sum over a 16-lane row via DPP (xor1, xor2, row_ror:4, row_ror:8) — all lanes get the sum
__device__ __forceinline__ float red16(float x) {
  int a;
  a = __builtin_amdgcn_update_dpp(0, __builtin_bit_cast(int, x), 0xB1, 0xF, 0xF, true);
  x += __builtin_bit_cast(float, a);
  a = __builtin_amdgcn_update_dpp(0, __builtin_bit_cast(int, x), 0x4E, 0xF, 0xF, true);
  x += __builtin_bit_cast(float, a);
  a = __builtin_amdgcn_update_dpp(0, __builtin_bit_cast(int, x), 0x124, 0xF, 0xF, true);
  x += __builtin_bit_cast(float, a);
  a = __builtin_amdgcn_update_dpp(0, __builtin_bit_cast(int, x), 0x128, 0xF, 0xF, true);
  x += __builtin_bit_cast(float, a);
  return x;
}
__device__ __forceinline__ f32x4 red16v(f32x4 v) {
  v[0] = red16(v[0]); v[1] = red16(v[1]);
  v[2] = red16(v[2]); v[3] = red16(v[3]);
  return v;
}

// ---------------- weights fp32 -> bf16 (all four in one launch) ----------------
__global__ __launch_bounds__(256)
void conv_bf16_k(const float* __restrict__ s0, const float* __restrict__ s1,
                 const float* __restrict__ s2, const float* __restrict__ s3,
                 u16* __restrict__ d0) {
  const float* s = (blockIdx.y == 0) ? s0 : (blockIdx.y == 1) ? s1
                   : (blockIdx.y == 2) ? s2 : s3;
  u16* d = d0 + (size_t)blockIdx.y * 4194304;
  int i = (blockIdx.x * 256 + threadIdx.x) * 8;
  f32x4 a = *(const f32x4*)(s + i);
  f32x4 b = *(const f32x4*)(s + i + 4);
  u16x8 o;
  o[0] = f2bf(a[0]); o[1] = f2bf(a[1]); o[2] = f2bf(a[2]); o[3] = f2bf(a[3]);
  o[4] = f2bf(b[0]); o[5] = f2bf(b[1]); o[6] = f2bf(b[2]); o[7] = f2bf(b[3]);
  *(u16x8*)(d + i) = o;
}

// ---------------- LoRA-down matrices: (C x 8) -> (8 x C) fp32 transpose ----------------
__global__ __launch_bounds__(256)
void trans_lora_k(const float* __restrict__ w1, const float* __restrict__ a1,
                  const float* __restrict__ v1, const float* __restrict__ g1,
                  float* __restrict__ wt) {
  const float* s = (blockIdx.y == 0) ? w1 : (blockIdx.y == 1) ? a1
                   : (blockIdx.y == 2) ? v1 : g1;
  float* d = wt + (size_t)blockIdx.y * (8 * C_DIM);
  int c = blockIdx.x * 256 + threadIdx.x;    // grid.x = 8
  f32x4 lo = *(const f32x4*)(s + c * 8);
  f32x4 hi = *(const f32x4*)(s + c * 8 + 4);
  d[0 * C_DIM + c] = lo[0]; d[1 * C_DIM + c] = lo[1];
  d[2 * C_DIM + c] = lo[2]; d[3 * C_DIM + c] = lo[3];
  d[4 * C_DIM + c] = hi[0]; d[5 * C_DIM + c] = hi[1];
  d[6 * C_DIM + c] = hi[2]; d[7 * C_DIM + c] = hi[3];
}

// ---------------- mix + LoRA down: 2 rows per block (tables read once per pair) ----------------
__global__ __launch_bounds__(256)
void mix_lora_k(const float* __restrict__ x,
                const float* __restrict__ xrw, const float* __restrict__ xww,
                const float* __restrict__ xkw, const float* __restrict__ xvw,
                const float* __restrict__ xaw, const float* __restrict__ xgw,
                const float* __restrict__ wt,   // 4 transposed tables, 8xC each
                u16* __restrict__ xr_bf, u16* __restrict__ xk_bf,
                u16* __restrict__ xv_bf, float* __restrict__ lora8) {
  const int pr = blockIdx.x * 2;          // rows pr, pr+1 (t0 even)
  const int t0 = pr & (T_LEN - 1);
  const int tid = threadIdx.x;
  const float* xr0 = x + (size_t)pr * C_DIM;
  const float* xr1 = xr0 + C_DIM;
  float wl0[8], al0[8], vl0[8], gl0[8];
  float wl1[8], al1[8], vl1[8], gl1[8];
  #pragma unroll
  for (int l = 0; l < 8; ++l) {
    wl0[l] = 0.f; al0[l] = 0.f; vl0[l] = 0.f; gl0[l] = 0.f;
    wl1[l] = 0.f; al1[l] = 0.f; vl1[l] = 0.f; gl1[l] = 0.f;
  }
  #pragma unroll
  for (int ii = 0; ii < 8; ++ii) {
    const int c = ii * 256 + tid;
    float x0 = xr0[c], x1 = xr1[c];
    float xm = t0 ? xr0[c - C_DIM] : 0.f;
    float dx0 = xm - x0;
    float dx1 = x0 - x1;
    float mr = xrw[c], mw = xww[c], mk = xkw[c];
    float mv = xvw[c], ma = xaw[c], mg = xgw[c];
    float xw0 = fmaf(dx0, mw, x0), xw1 = fmaf(dx1, mw, x1);
    float xa0 = fmaf(dx0, ma, x0), xa1 = fmaf(dx1, ma, x1);
    float xv0 = fmaf(dx0, mv, x0), xv1 = fmaf(dx1, mv, x1);
    float xg0 = fmaf(dx0, mg, x0), xg1 = fmaf(dx1, mg, x1);
    xr_bf[(size_t)pr * C_DIM + c] = f2bf(fmaf(dx0, mr, x0));
    xr_bf[(size_t)(pr + 1) * C_DIM + c] = f2bf(fmaf(dx1, mr, x1));
    xk_bf[(size_t)pr * C_DIM + c] = f2bf(fmaf(dx0, mk, x0));
    xk_bf[(size_t)(pr + 1) * C_DIM + c] = f2bf(fmaf(dx1, mk, x1));
    xv_bf[(size_t)pr * C_DIM + c] = f2bf(xv0);
    xv_bf[(size_t)(pr + 1) * C_DIM + c] = f2bf(xv1);
    #pragma unroll
    for (int l = 0; l < 8; ++l) {
      float tw = wt[l * C_DIM + c];
      float ta = wt[16384 + l * C_DIM + c];
      float tv = wt[32768 + l * C_DIM + c];
      float tg = wt[49152 + l * C_DIM + c];
      wl0[l] = fmaf(xw0, tw, wl0[l]); wl1[l] = fmaf(xw1, tw, wl1[l]);
      al0[l] = fmaf(xa0, ta, al0[l]); al1[l] = fmaf(xa1, ta, al1[l]);
      vl0[l] = fmaf(xv0, tv, vl0[l]); vl1[l] = fmaf(xv1, tv, vl1[l]);
      gl0[l] = fmaf(xg0, tg, gl0[l]); gl1[l] = fmaf(xg1, tg, gl1[l]);
    }
  }
  __shared__ __attribute__((aligned(16))) float red2[2][16][32];
  const int row = tid >> 4;
  // row-reduce (16 lanes) all partials via DPP — pure VALU
  f32x4 t0v, t1v;
  #pragma unroll
  for (int half = 0; half < 2; ++half) {
    float* wl = half ? wl1 : wl0;
    float* al = half ? al1 : al0;
    float* vl = half ? vl1 : vl0;
    float* gl = half ? gl1 : gl0;
    t0v = red16v((f32x4){wl[0], wl[1], wl[2], wl[3]});
    t1v = red16v((f32x4){wl[4], wl[5], wl[6], wl[7]});
    if ((tid & 15) == 0) {
      *(f32x4*)&red2[half][row][0] = t0v; *(f32x4*)&red2[half][row][4] = t1v;
    }
    t0v = red16v((f32x4){al[0], al[1], al[2], al[3]});
    t1v = red16v((f32x4){al[4], al[5], al[6], al[7]});
    if ((tid & 15) == 0) {
      *(f32x4*)&red2[half][row][8] = t0v; *(f32x4*)&red2[half][row][12] = t1v;
    }
    t0v = red16v((f32x4){vl[0], vl[1], vl[2], vl[3]});
    t1v = red16v((f32x4){vl[4], vl[5], vl[6], vl[7]});
    if ((tid & 15) == 0) {
      *(f32x4*)&red2[half][row][16] = t0v; *(f32x4*)&red2[half][row][20] = t1v;
    }
    t0v = red16v((f32x4){gl[0], gl[1], gl[2], gl[3]});
    t1v = red16v((f32x4){gl[4], gl[5], gl[6], gl[7]});
    if ((tid & 15) == 0) {
      *(f32x4*)&red2[half][row][24] = t0v; *(f32x4*)&red2[half][row][28] = t1v;
    }
  }
  __syncthreads();
  if (tid < 64) {
    const int rw = tid >> 5, idx = tid & 31;
    float s = 0.f;
    #pragma unroll
    for (int r = 0; r < 16; ++r) s += red2[rw][r][idx];
    int mat = idx >> 3;
    if (mat == 0) s = tanhf(s);
    else if (mat == 3) s = 1.f / (1.f + expf(-s));
    lora8[(size_t)(pr + rw) * 32 + idx] = s;
  }
}

// ---------------- 256x256 8-wave double-buffered MFMA GEMM (2-3 phase pipeline) ----------------
__device__ __forceinline__ int swzslot(int row, int slot) {
  return slot ^ ((row >> 1) & 3);
}

__global__ __launch_bounds__(512)
void gemm8_k(const u16* __restrict__ A0, const u16* __restrict__ A1,
             const u16* __restrict__ A2, const u16* __restrict__ B0,
             const u16* __restrict__ B1, const u16* __restrict__ B2,
             char* __restrict__ out, int pmode) {
  extern __shared__ __attribute__((aligned(16))) char smem[];
  u16* Asm = (u16*)smem;               // [db][kh][8192] u16  (64 KB)
  u16* Bsm = (u16*)(smem + 65536);     // [db][kh][8192] u16  (64 KB)
  const int z = blockIdx.z;
  const u16* A = (z == 0) ? A0 : (z == 1) ? A1 : A2;
  const u16* Bw = (z == 0) ? B0 : (z == 1) ? B1 : B2;
  const int sbase = (z == 0) ? 4 : (z == 1) ? 6 : 192;
  const int sstr = (z == 2) ? 2 : 8;
  const int tid = threadIdx.x;
  const int wv = tid >> 6, ln = tid & 63;
  const int wr = wv >> 2, wc = wv & 3;         // 2 x 4 wave grid
  // XCD-bijective swizzle of the 8x32 tile grid (nwg=256, 256%8==0)
  const int bid = blockIdx.x + (blockIdx.y << 3);
  const int sw = (bid & 7) * 32 + (bid >> 3);
  const int row0 = (sw >> 3) * 256, col0 = (sw & 7) * 256;
  const int s_rw = tid >> 2;
  const int s_slotL = (tid & 3) ^ ((s_rw >> 1) & 3);   // logical slot fetched
  int aoff[8], boff[4];
  #pragma unroll
  for (int m = 0; m < 8; ++m) {
    int row = wr * 128 + m * 16 + (ln & 15);
    aoff[m] = row * 32 + swzslot(row, ln >> 4) * 8;
  }
  #pragma unroll
  for (int n = 0; n < 4; ++n) {
    int row = wc * 64 + n * 16 + (ln & 15);
    boff[n] = row * 32 + swzslot(row, ln >> 4) * 8;
  }
  f32x4 acc[8][4];
  #pragma unroll
  for (int m = 0; m < 8; ++m)
    #pragma unroll
    for (int n = 0; n < 4; ++n) acc[m][n] = (f32x4){0.f, 0.f, 0.f, 0.f};

  auto abase = [&](int db, int kh) -> u16* { return Asm + (db * 2 + kh) * 8192; };
  auto bbase = [&](int db, int kh) -> u16* { return Bsm + (db * 2 + kh) * 8192; };
  auto stage1 = [&](const u16* src, int baserow, u16* lbase, int kh, int skt, int rblk) {
    const u16* g = src + (size_t)(baserow + rblk * 128 + s_rw) * 2048
                   + skt * 64 + kh * 32 + s_slotL * 8;
    gld16(g, lbase + rblk * 4096 + wv * 512);
  };
  // kh0 compute phase; stages the FULL next tile (8 loads: kh0 group first)
  auto khblockA = [&](int db, int skt, bool doStage) {
    const u16* Ab = abase(db, 0);
    const u16* Bb = bbase(db, 0);
    const int sdb = skt & 1;
    bf16x8 bf[4], af[4];
    #pragma unroll
    for (int n = 0; n < 4; ++n) bf[n] = *(const bf16x8*)(Bb + boff[n]);
    #pragma unroll
    for (int m = 0; m < 4; ++m) af[m] = *(const bf16x8*)(Ab + aoff[m]);
    if (doStage) {
      stage1(A, row0, abase(sdb, 0), 0, skt, 0);
      stage1(A, row0, abase(sdb, 0), 0, skt, 1);
      stage1(Bw, col0, bbase(sdb, 0), 0, skt, 0);
      stage1(Bw, col0, bbase(sdb, 0), 0, skt, 1);
    }
    __builtin_amdgcn_s_setprio(1);
    #pragma unroll
    for (int m = 0; m < 4; ++m)
      #pragma unroll
      for (int n = 0; n < 4; ++n)
        acc[m][n] = __builtin_amdgcn_mfma_f32_16x16x32_bf16(af[m], bf[n], acc[m][n], 0, 0, 0);
    __builtin_amdgcn_s_setprio(0);
    #pragma unroll
    for (int m = 0; m < 4; ++m) af[m] = *(const bf16x8*)(Ab + aoff[4 + m]);
    if (doStage) {
      stage1(A, row0, abase(sdb, 1), 1, skt, 0);
      stage1(A, row0, abase(sdb, 1), 1, skt, 1);
      stage1(Bw, col0, bbase(sdb, 1), 1, skt, 0);
      stage1(Bw, col0, bbase(sdb, 1), 1, skt, 1);
    }
    __builtin_amdgcn_s_setprio(1);
    #pragma unroll
    for (int m = 0; m < 4; ++m)
      #pragma unroll
      for (int n = 0; n < 4; ++n)
        acc[4 + m][n] = __builtin_amdgcn_mfma_f32_16x16x32_bf16(af[m], bf[n], acc[4 + m][n], 0, 0, 0);
    __builtin_amdgcn_s_setprio(0);
  };
  // kh1 compute phase (no staging)
  auto khblockB = [&](int db) {
    const u16* Ab = abase(db, 1);
    const u16* Bb = bbase(db, 1);
    bf16x8 bf[4], af[4];
    #pragma unroll
    for (int n = 0; n < 4; ++n) bf[n] = *(const bf16x8*)(Bb + boff[n]);
    #pragma unroll
    for (int m = 0; m < 4; ++m) af[m] = *(const bf16x8*)(Ab + aoff[m]);
    __builtin_amdgcn_s_setprio(1);
    #pragma unroll
    for (int m = 0; m < 4; ++m)
      #pragma unroll
      for (int n = 0; n < 4; ++n)
        acc[m][n] = __builtin_amdgcn_mfma_f32_16x16x32_bf16(af[m], bf[n], acc[m][n], 0, 0, 0);
    __builtin_amdgcn_s_setprio(0);
    #pragma unroll
    for (int m = 0; m < 4; ++m) af[m] = *(const bf16x8*)(Ab + aoff[4 + m]);
    __builtin_amdgcn_s_setprio(1);
    #pragma unroll
    for (int m = 0; m < 4; ++m)
      #pragma unroll
      for (int n = 0; n < 4; ++n)
        acc[4 + m][n] = __builtin_amdgcn_mfma_f32_16x16x32_bf16(af[m], bf[n], acc[4 + m][n], 0, 0, 0);
    __builtin_amdgcn_s_setprio(0);
  };

  // prologue: stage tile 0 (kh0 group first)
  stage1(A, row0, abase(0, 0), 0, 0, 0); stage1(A, row0, abase(0, 0), 0, 0, 1);
  stage1(Bw, col0, bbase(0, 0), 0, 0, 0); stage1(Bw, col0, bbase(0, 0), 0, 0, 1);
  stage1(A, row0, abase(0, 1), 1, 0, 0); stage1(A, row0, abase(0, 1), 1, 0, 1);
  stage1(Bw, col0, bbase(0, 1), 1, 0, 0); stage1(Bw, col0, bbase(0, 1), 1, 0, 1);
  asm volatile("s_waitcnt vmcnt(4)" ::: "memory");
  __builtin_amdgcn_s_barrier();
  for (int kt = 0; kt < 32; ++kt) {
    const int db = kt & 1;
    khblockA(db, kt + 1, kt < 31);
    if (kt < 31) asm volatile("s_waitcnt vmcnt(8)" ::: "memory");
    else         asm volatile("s_waitcnt vmcnt(0)" ::: "memory");
    __builtin_amdgcn_s_barrier();
    khblockB(db);
    if (kt < 31) {
      asm volatile("s_waitcnt vmcnt(4)" ::: "memory");
      __builtin_amdgcn_s_barrier();
    }
  }

  const int rowb = row0 + wr * 128 + ((ln >> 4) << 2);
  const int colb = col0 + wc * 64 + (ln & 15);
  #pragma unroll
  for (int m = 0; m < 8; ++m)
    #pragma unroll
    for (int n = 0; n < 4; ++n)
      #pragma unroll
      for (int qq = 0; qq < 4; ++qq) {
        int row = rowb + m * 16 + qq;
        int col = colb + n * 16;
        float val = acc[m][n][qq];
        if (pmode == 0) {
          ((float*)out)[(size_t)row * 2048 + col] = val;
        } else {
          int bq = row >> 12, tq = row & (T_LEN - 1);
          int hq = col >> 4, jq = col & 15;
          *(u16*)(out + (size_t)((bq * 128 + hq) * T_LEN + tq) * REC
                  + sbase + jq * sstr) = f2bf(val);
        }
      }
}

// ---------------- post-GEMM: LoRA-up, decay, v-mix, kk-norm (coalesced module mapping) ----------------
__global__ __launch_bounds__(256)
void post_gemm_k(const float* __restrict__ v_first, const float* __restrict__ lora8,
                 const float* __restrict__ w0, const float* __restrict__ w2,
                 const float* __restrict__ a0, const float* __restrict__ a2,
                 const float* __restrict__ v0, const float* __restrict__ v2,
                 const float* __restrict__ k_k, const float* __restrict__ k_a,
                 char* __restrict__ packed) {
  const int tg = blockIdx.x;          // 0..1023 (4 t each)
  const int mo = blockIdx.y;          // module 0..31 (64 channels)
  const int bq = blockIdx.z;
  const int tid = threadIdx.x;
  const int wv = tid >> 6, ln = tid & 63;
  const int t = tg * 4 + wv;
  const int cc = ln & 15;
  const int hq = mo * 4 + (ln >> 4);
  const int c = mo * 64 + ln;
  char* pb = packed + (size_t)((bq * 128 + hq) * T_LEN + t) * REC;
  const int rr = bq * T_LEN + t;
  u32 kr = *(const u32*)(pb + cc * 8 + 4);
  float kraw = bflo(kr);
  float vraw = bflo(*(const u16*)(pb + 192 + cc * 2));
  float vf = v_first[(size_t)rr * C_DIM + c];
  const float* lo = lora8 + (size_t)rr * 32;
  float wr_ = w0[c], ar_ = a0[c], vr_ = v0[c];
  #pragma unroll
  for (int l = 0; l < 8; ++l) {
    wr_ = fmaf(lo[l], w2[l * C_DIM + c], wr_);
    ar_ = fmaf(lo[8 + l], a2[l * C_DIM + c], ar_);
    vr_ = fmaf(lo[16 + l], v2[l * C_DIM + c], vr_);
  }
  float w_ = -log1pf(expf(-wr_)) - 0.5f;
  float dec = expf(-expf(w_));
  float a_ = 1.f / (1.f + expf(-ar_));
  float vm = 1.f / (1.f + expf(-vr_));
  float vnew = fmaf(vf - vraw, vm, vraw);
  float kk = kraw * k_k[c];
  float ss = red16(kk * kk);
  ss += __shfl_xor(ss, 16);
  ss += __shfl_xor(ss, 32);
  float sc = 1.f / fmaxf(sqrtf(ss), 1e-8f);
  float kn = kk * sc;
  u16 wa = f2bf(-kn);
  u16 wb = f2bf(kn * a_);
  u16 wk = f2bf(kraw * fmaf(a_ - 1.f, k_a[c], 1.f));
  *(u32*)(pb + cc * 8) = (u32)wa | ((u32)wb << 16);
  *(u32*)(pb + cc * 8 + 4) = (u32)wk | (kr & 0xffff0000u);
  *(u16*)(pb + 192 + cc * 2) = f2bf(vnew);
  *(float*)(pb + 128 + cc * 4) = dec;
}

// ---------------- sequential RWKV7 scan: 1 head / 4-wave block, 1 elem/lane ----------------
__device__ __forceinline__ void stage(const char* g, char* l, int wv, int ln) {
  gld16(g + wv * 1024 + ln * 16, l + wv * 1024);
  gld16(g + 4096 + wv * 1024 + ln * 16, l + 4096 + wv * 1024);
  gld16(g + 8192 + wv * 1024 + ln * 16, l + 8192 + wv * 1024);
  if (wv < 2) gld16(g + 12288 + wv * 1024 + ln * 16, l + 12288 + wv * 1024);
}

__global__ __launch_bounds__(256)
void scan_k(char* __restrict__ packed) {
  // 2 chunk halves + 1 KB pad so distance-4 over-reads stay in-bounds
  __shared__ __attribute__((aligned(16))) char bufm[2 * CHB + 1024];
  __shared__ __attribute__((aligned(16))) float ybuf[CH * 16];
  const int hb = blockIdx.x;
  const int tid = threadIdx.x;
  const int wv = tid >> 6, ln = tid & 63;
  const int j = ln & 15;
  const int i = wv * 4 + (ln >> 4);
  char* src = packed + (size_t)hb * (T_LEN * REC);
  float S = 0.f;
  stage(src, bufm, wv, ln);
  const int NC = T_LEN / CH;
  for (int c = 0; c < NC; ++c) {
    asm volatile("s_waitcnt vmcnt(0)" ::: "memory");
    __syncthreads();
    if (c + 1 < NC)
      stage(src + (size_t)(c + 1) * CHB, bufm + ((c + 1) & 1) * CHB, wv, ln);
    const char* Bp = bufm + (c & 1) * CHB;
    const char* p0 = Bp + j * 8;         // [a|b][k|r] packet, +t*REC
    const char* pd = Bp + 128 + j * 4;   // dec f32
    const char* pv = Bp + 192 + i * 2;   // v bf16
    // preload steps 0..3
    u32x2 kq[4]; float dq[4]; u32 vq[4];
    #pragma unroll
    for (int s = 0; s < 4; ++s) {
      kq[s] = *(const u32x2*)(p0 + s * REC);
      dq[s] = *(const float*)(pd + s * REC);
      vq[s] = *(const u16*)(pv + s * REC);
    }
    float yq0 = 0.f, yq1 = 0.f, yq2 = 0.f, yq3 = 0.f;
    #pragma unroll
    for (int t = 0; t < CH; ++t) {
      const int st = t & 3;
      u32x2 kc = kq[st]; float dc = dq[st]; u32 vc = vq[st];
      // prefetch t+4 (tail over-reads land in pad; re-preloaded next chunk)
      kq[st] = *(const u32x2*)(p0 + (t + 4) * REC);
      dq[st] = *(const float*)(pd + (t + 4) * REC);
      vq[st] = *(const u16*)(pv + (t + 4) * REC);
      float a_ = bflo(kc[0]), b_ = bfhi(kc[0]);
      float k_ = bflo(kc[1]), r_ = bfhi(kc[1]);
      float v_ = bflo(vc);
      float sa = red16(S * a_);
      S = fmaf(S, dc, fmaf(sa, b_, v_ * k_));
      float yv = red16(S * r_);
      const bool own = (j == (t & 15));
      if ((t >> 4) == 0)      yq0 = own ? yv : yq0;
      else if ((t >> 4) == 1) yq1 = own ? yv : yq1;
      else if ((t >> 4) == 2) yq2 = own ? yv : yq2;
      else                    yq3 = own ? yv : yq3;
    }
    // dump register y to ybuf: value yqQ holds y for (t = Q*16 + j, row i)
    ybuf[(0 * 16 + j) * 16 + i] = yq0;
    ybuf[(1 * 16 + j) * 16 + i] = yq1;
    ybuf[(2 * 16 + j) * 16 + i] = yq2;
    ybuf[(3 * 16 + j) * 16 + i] = yq3;
    __syncthreads();
    // coalesced y flush: thread -> record tid>>2, 16B part tid&3
    {
      const int rec = tid >> 2, part = tid & 3;
      f32x4 y4 = *(const f32x4*)(ybuf + rec * 16 + part * 4);
      *(f32x4*)(src + (size_t)c * CHB + rec * REC + 128 + part * 16) = y4;
    }
  }
}

// ---------------- GroupNorm + residual + gate -> bf16 (coalesced module mapping) ----------------
__global__ __launch_bounds__(256)
void post_gn_k(const char* __restrict__ packed, const float* __restrict__ lora8,
               const float* __restrict__ g2, const float* __restrict__ ln_g,
               const float* __restrict__ ln_b, const float* __restrict__ r_k,
               u16* __restrict__ og) {
  const int tg = blockIdx.x;          // 0..1023 (4 t each)
  const int mo = blockIdx.y;          // module 0..31 (64 channels)
  const int bq = blockIdx.z;
  const int tid = threadIdx.x;
  const int wv = tid >> 6, ln = tid & 63;
  const int t = tg * 4 + wv;
  const int cc = ln & 15;
  const int hq = mo * 4 + (ln >> 4);
  const int c = mo * 64 + ln;
  const char* pb = packed + (size_t)((bq * 128 + hq) * T_LEN + t) * REC;
  u32 kr = *(const u32*)(pb + cc * 8 + 4);
  float kv = bflo(kr), rv = bfhi(kr);
  float vv = bflo(*(const u16*)(pb + 192 + cc * 2));
  float o = *(const float*)(pb + 128 + cc * 4);
  const int rr = bq * T_LEN + t;
  const float* lo = lora8 + (size_t)rr * 32 + 24;
  float gg = 0.f;
  #pragma unroll
  for (int l = 0; l < 8; ++l) gg = fmaf(lo[l], g2[l * C_DIM + c], gg);
  float s1 = red16(o);
  float s2 = red16(o * o);
  float srk = red16(rv * kv * r_k[c]);
  s1 += __shfl_xor(s1, 16); s2 += __shfl_xor(s2, 16); srk += __shfl_xor(srk, 16);
  s1 += __shfl_xor(s1, 32); s2 += __shfl_xor(s2, 32); srk += __shfl_xor(srk, 32);
  float mu = s1 * (1.f / 64.f);
  float var = s2 * (1.f / 64.f) - mu * mu;
  float rstd = rsqrtf(var + 0.00064f);
  float on = fmaf((o - mu) * rstd, ln_g[c], ln_b[c]);
  float o2 = fmaf(srk, vv, on);
  og[(size_t)rr * C_DIM + c] = f2bf(o2 * gg);
}

extern "C" void kernel_launch(void* const* d_in, const int* in_sizes, int n_in,
                              void* d_out, int out_size, void* d_ws, size_t ws_size,
                              hipStream_t stream) {
  (void)in_sizes; (void)n_in; (void)out_size;
  const float* x      = (const float*)d_in[0];
  const float* v_first= (const float*)d_in[1];
  const float* x_r    = (const float*)d_in[2];
  const float* x_w    = (const float*)d_in[3];
  const float* x_k    = (const float*)d_in[4];
  const float* x_v    = (const float*)d_in[5];
  const float* x_a    = (const float*)d_in[6];
  const float* x_g    = (const float*)d_in[7];
  const float* w0     = (const float*)d_in[8];
  const float* w1     = (const float*)d_in[9];
  const float* w2     = (const float*)d_in[10];
  const float* a0     = (const float*)d_in[11];
  const float* a1     = (const float*)d_in[12];
  const float* a2     = (const float*)d_in[13];
  const float* v0     = (const float*)d_in[14];
  const float* v1     = (const float*)d_in[15];
  const float* v2     = (const float*)d_in[16];
  const float* g1     = (const float*)d_in[17];
  const float* g2     = (const float*)d_in[18];
  const float* k_k    = (const float*)d_in[19];
  const float* k_a    = (const float*)d_in[20];
  const float* r_k    = (const float*)d_in[21];
  const float* Wr     = (const float*)d_in[22];
  const float* Wk     = (const float*)d_in[23];
  const float* Wv     = (const float*)d_in[24];
  const float* Wo     = (const float*)d_in[25];
  const float* ln_g   = (const float*)d_in[26];
  const float* ln_b   = (const float*)d_in[27];

  if (ws_size < 370147328ull) return;
  char* ws = (char*)d_ws;
  u16* Wr_bf = (u16*)(ws + 0);            //  8 MB each, contiguous (conv indexes)
  u16* Wk_bf = Wr_bf + 4194304;
  u16* Wv_bf = Wk_bf + 4194304;
  u16* Wo_bf = Wv_bf + 4194304;
  u16* xr_bf = (u16*)(ws + 33554432);     // 32 MB each
  u16* xk_bf = xr_bf + 16777216;
  u16* xv_bf = xk_bf + 16777216;
  float* lora8 = (float*)(ws + 134217728); // 1 MB
  char* packed = ws + 135266304;           // 224 MB
  float* wt = (float*)packed;              // transposed LoRA tables (256 KB),
                                           // consumed before gemms overwrite
  u16* og = xr_bf;                         // reuse (dead after r-GEMM)
  float* out = (float*)d_out;

  (void)hipFuncSetAttribute((const void*)gemm8_k,
                            hipFuncAttributeMaxDynamicSharedMemorySize, 131072);

  conv_bf16_k<<<dim3(2048, 4), 256, 0, stream>>>(Wr, Wk, Wv, Wo, Wr_bf);
  trans_lora_k<<<dim3(8, 4), 256, 0, stream>>>(w1, a1, v1, g1, wt);

  mix_lora_k<<<4096, 256, 0, stream>>>(x, x_r, x_w, x_k, x_v, x_a, x_g,
                                       wt, xr_bf, xk_bf, xv_bf, lora8);

  gemm8_k<<<dim3(8, 32, 3), 512, 131072, stream>>>(xk_bf, xr_bf, xv_bf,
                                                   Wk_bf, Wr_bf, Wv_bf,
                                                   packed, 1);

  post_gemm_k<<<dim3(1024, 32, 2), 256, 0, stream>>>(v_first, lora8, w0, w2,
                                                     a0, a2, v0, v2,
                                                     k_k, k_a, packed);

  scan_k<<<256, 256, 0, stream>>>(packed);

  post_gn_k<<<dim3(1024, 32, 2), 256, 0, stream>>>(packed, lora8, g2,
                                                   ln_g, ln_b, r_k, og);

  gemm8_k<<<dim3(8, 32, 1), 512, 131072, stream>>>(og, og, og,
                                                   Wo_bf, Wo_bf, Wo_bf,
                                                   (char*)out, 0);

  hipMemcpyAsync(out + 16777216, v_first, (size_t)16777216 * 4,
                 hipMemcpyDeviceToDevice, stream);
}

// Round 17
// 1081.990 us; speedup vs baseline: 1.2923x; 1.0437x over previous
//
#include <hip/hip_runtime.h>

#define T_LEN 4096
#define C_DIM 2048
#define REC 224          // packed record: 16x[a,b,k,r] bf16 128B | dec/y f32 64B | v bf16 32B
#define CH 64            // scan steps per LDS chunk (64*224 = 14336 B)
#define CHB (CH * REC)

typedef __attribute__((ext_vector_type(4))) float f32x4;
typedef __attribute__((ext_vector_type(8))) __bf16 bf16x8;
typedef __attribute__((ext_vector_type(8))) unsigned short u16x8;
typedef __attribute__((ext_vector_type(4))) unsigned int u32x4;
typedef __attribute__((ext_vector_type(2))) unsigned int u32x2;
typedef unsigned short u16;
typedef unsigned int u32;

typedef __attribute__((address_space(1))) const void* as1cv;
typedef __attribute__((address_space(3))) void* as3v;

__device__ __forceinline__ void gld16(const void* g, void* l) {
  __builtin_amdgcn_global_load_lds((as1cv)g, (as3v)l, 16, 0, 0);
}

__device__ __forceinline__ u16 f2bf(float f) {
  union { float f; unsigned u; } x; x.f = f;
  return (u16)((x.u + 0x7fffu + ((x.u >> 16) & 1u)) >> 16);
}
__device__ __forceinline__ float bflo(unsigned u) {
  union { unsigned u; float f; } x; x.u = u << 16; return x.f;
}
__device__ __forceinline__ float bfhi(unsigned u) {
  union { unsigned u; float f; } x; x.u = u & 0xffff0000u; return x.f;
}
// sum over a 16-lane row via DPP (xor1, xor2, row_ror:4, row_ror:8) — all lanes get the sum
__device__ __forceinline__ float red16(float x) {
  int a;
  a = __builtin_amdgcn_update_dpp(0, __builtin_bit_cast(int, x), 0xB1, 0xF, 0xF, true);
  x += __builtin_bit_cast(float, a);
  a = __builtin_amdgcn_update_dpp(0, __builtin_bit_cast(int, x), 0x4E, 0xF, 0xF, true);
  x += __builtin_bit_cast(float, a);
  a = __builtin_amdgcn_update_dpp(0, __builtin_bit_cast(int, x), 0x124, 0xF, 0xF, true);
  x += __builtin_bit_cast(float, a);
  a = __builtin_amdgcn_update_dpp(0, __builtin_bit_cast(int, x), 0x128, 0xF, 0xF, true);
  x += __builtin_bit_cast(float, a);
  return x;
}
__device__ __forceinline__ f32x4 red16v(f32x4 v) {
  v[0] = red16(v[0]); v[1] = red16(v[1]);
  v[2] = red16(v[2]); v[3] = red16(v[3]);
  return v;
}

// ---------------- weights fp32 -> bf16 (all four in one launch) ----------------
__global__ __launch_bounds__(256)
void conv_bf16_k(const float* __restrict__ s0, const float* __restrict__ s1,
                 const float* __restrict__ s2, const float* __restrict__ s3,
                 u16* __restrict__ d0) {
  const float* s = (blockIdx.y == 0) ? s0 : (blockIdx.y == 1) ? s1
                   : (blockIdx.y == 2) ? s2 : s3;
  u16* d = d0 + (size_t)blockIdx.y * 4194304;
  int i = (blockIdx.x * 256 + threadIdx.x) * 8;
  f32x4 a = *(const f32x4*)(s + i);
  f32x4 b = *(const f32x4*)(s + i + 4);
  u16x8 o;
  o[0] = f2bf(a[0]); o[1] = f2bf(a[1]); o[2] = f2bf(a[2]); o[3] = f2bf(a[3]);
  o[4] = f2bf(b[0]); o[5] = f2bf(b[1]); o[6] = f2bf(b[2]); o[7] = f2bf(b[3]);
  *(u16x8*)(d + i) = o;
}

// ---------------- LoRA-down matrices: (C x 8) -> (8 x C) fp32 transpose ----------------
__global__ __launch_bounds__(256)
void trans_lora_k(const float* __restrict__ w1, const float* __restrict__ a1,
                  const float* __restrict__ v1, const float* __restrict__ g1,
                  float* __restrict__ wt) {
  const float* s = (blockIdx.y == 0) ? w1 : (blockIdx.y == 1) ? a1
                   : (blockIdx.y == 2) ? v1 : g1;
  float* d = wt + (size_t)blockIdx.y * (8 * C_DIM);
  int c = blockIdx.x * 256 + threadIdx.x;    // grid.x = 8
  f32x4 lo = *(const f32x4*)(s + c * 8);
  f32x4 hi = *(const f32x4*)(s + c * 8 + 4);
  d[0 * C_DIM + c] = lo[0]; d[1 * C_DIM + c] = lo[1];
  d[2 * C_DIM + c] = lo[2]; d[3 * C_DIM + c] = lo[3];
  d[4 * C_DIM + c] = hi[0]; d[5 * C_DIM + c] = hi[1];
  d[6 * C_DIM + c] = hi[2]; d[7 * C_DIM + c] = hi[3];
}

// ---------------- mix + LoRA down: 2 rows per block (tables read once per pair) ----------------
__global__ __launch_bounds__(256)
void mix_lora_k(const float* __restrict__ x,
                const float* __restrict__ xrw, const float* __restrict__ xww,
                const float* __restrict__ xkw, const float* __restrict__ xvw,
                const float* __restrict__ xaw, const float* __restrict__ xgw,
                const float* __restrict__ wt,   // 4 transposed tables, 8xC each
                u16* __restrict__ xr_bf, u16* __restrict__ xk_bf,
                u16* __restrict__ xv_bf, float* __restrict__ lora8) {
  const int pr = blockIdx.x * 2;          // rows pr, pr+1 (t0 even)
  const int t0 = pr & (T_LEN - 1);
  const int tid = threadIdx.x;
  const float* xr0 = x + (size_t)pr * C_DIM;
  const float* xr1 = xr0 + C_DIM;
  float wl0[8], al0[8], vl0[8], gl0[8];
  float wl1[8], al1[8], vl1[8], gl1[8];
  #pragma unroll
  for (int l = 0; l < 8; ++l) {
    wl0[l] = 0.f; al0[l] = 0.f; vl0[l] = 0.f; gl0[l] = 0.f;
    wl1[l] = 0.f; al1[l] = 0.f; vl1[l] = 0.f; gl1[l] = 0.f;
  }
  #pragma unroll
  for (int ii = 0; ii < 8; ++ii) {
    const int c = ii * 256 + tid;
    float x0 = xr0[c], x1 = xr1[c];
    float xm = t0 ? xr0[c - C_DIM] : 0.f;
    float dx0 = xm - x0;
    float dx1 = x0 - x1;
    float mr = xrw[c], mw = xww[c], mk = xkw[c];
    float mv = xvw[c], ma = xaw[c], mg = xgw[c];
    float xw0 = fmaf(dx0, mw, x0), xw1 = fmaf(dx1, mw, x1);
    float xa0 = fmaf(dx0, ma, x0), xa1 = fmaf(dx1, ma, x1);
    float xv0 = fmaf(dx0, mv, x0), xv1 = fmaf(dx1, mv, x1);
    float xg0 = fmaf(dx0, mg, x0), xg1 = fmaf(dx1, mg, x1);
    xr_bf[(size_t)pr * C_DIM + c] = f2bf(fmaf(dx0, mr, x0));
    xr_bf[(size_t)(pr + 1) * C_DIM + c] = f2bf(fmaf(dx1, mr, x1));
    xk_bf[(size_t)pr * C_DIM + c] = f2bf(fmaf(dx0, mk, x0));
    xk_bf[(size_t)(pr + 1) * C_DIM + c] = f2bf(fmaf(dx1, mk, x1));
    xv_bf[(size_t)pr * C_DIM + c] = f2bf(xv0);
    xv_bf[(size_t)(pr + 1) * C_DIM + c] = f2bf(xv1);
    #pragma unroll
    for (int l = 0; l < 8; ++l) {
      float tw = wt[l * C_DIM + c];
      float ta = wt[16384 + l * C_DIM + c];
      float tv = wt[32768 + l * C_DIM + c];
      float tg = wt[49152 + l * C_DIM + c];
      wl0[l] = fmaf(xw0, tw, wl0[l]); wl1[l] = fmaf(xw1, tw, wl1[l]);
      al0[l] = fmaf(xa0, ta, al0[l]); al1[l] = fmaf(xa1, ta, al1[l]);
      vl0[l] = fmaf(xv0, tv, vl0[l]); vl1[l] = fmaf(xv1, tv, vl1[l]);
      gl0[l] = fmaf(xg0, tg, gl0[l]); gl1[l] = fmaf(xg1, tg, gl1[l]);
    }
  }
  __shared__ __attribute__((aligned(16))) float red2[2][16][32];
  const int row = tid >> 4;
  // row-reduce (16 lanes) all partials via DPP — pure VALU
  f32x4 t0v, t1v;
  #pragma unroll
  for (int half = 0; half < 2; ++half) {
    float* wl = half ? wl1 : wl0;
    float* al = half ? al1 : al0;
    float* vl = half ? vl1 : vl0;
    float* gl = half ? gl1 : gl0;
    t0v = red16v((f32x4){wl[0], wl[1], wl[2], wl[3]});
    t1v = red16v((f32x4){wl[4], wl[5], wl[6], wl[7]});
    if ((tid & 15) == 0) {
      *(f32x4*)&red2[half][row][0] = t0v; *(f32x4*)&red2[half][row][4] = t1v;
    }
    t0v = red16v((f32x4){al[0], al[1], al[2], al[3]});
    t1v = red16v((f32x4){al[4], al[5], al[6], al[7]});
    if ((tid & 15) == 0) {
      *(f32x4*)&red2[half][row][8] = t0v; *(f32x4*)&red2[half][row][12] = t1v;
    }
    t0v = red16v((f32x4){vl[0], vl[1], vl[2], vl[3]});
    t1v = red16v((f32x4){vl[4], vl[5], vl[6], vl[7]});
    if ((tid & 15) == 0) {
      *(f32x4*)&red2[half][row][16] = t0v; *(f32x4*)&red2[half][row][20] = t1v;
    }
    t0v = red16v((f32x4){gl[0], gl[1], gl[2], gl[3]});
    t1v = red16v((f32x4){gl[4], gl[5], gl[6], gl[7]});
    if ((tid & 15) == 0) {
      *(f32x4*)&red2[half][row][24] = t0v; *(f32x4*)&red2[half][row][28] = t1v;
    }
  }
  __syncthreads();
  if (tid < 64) {
    const int rw = tid >> 5, idx = tid & 31;
    float s = 0.f;
    #pragma unroll
    for (int r = 0; r < 16; ++r) s += red2[rw][r][idx];
    int mat = idx >> 3;
    if (mat == 0) s = tanhf(s);
    else if (mat == 3) s = 1.f / (1.f + expf(-s));
    lora8[(size_t)(pr + rw) * 32 + idx] = s;
  }
}

// ---------------- 256x256 8-wave MFMA GEMM: BK=32 tiles, triple buffer, depth-2 pipeline ----------------
__device__ __forceinline__ int swzslot(int row, int slot) {
  return slot ^ ((row >> 1) & 3);
}

__global__ __launch_bounds__(512)
void gemm8_k(const u16* __restrict__ A0, const u16* __restrict__ A1,
             const u16* __restrict__ A2, const u16* __restrict__ B0,
             const u16* __restrict__ B1, const u16* __restrict__ B2,
             char* __restrict__ out, int pmode) {
  extern __shared__ __attribute__((aligned(16))) char smem[];
  // 3 buffers x 32 KB; buffer b: A u16[8192] at b*16384, B u16[8192] at b*16384+8192
  const int z = blockIdx.z;
  const u16* A = (z == 0) ? A0 : (z == 1) ? A1 : A2;
  const u16* Bw = (z == 0) ? B0 : (z == 1) ? B1 : B2;
  const int sbase = (z == 0) ? 4 : (z == 1) ? 6 : 192;
  const int sstr = (z == 2) ? 2 : 8;
  const int tid = threadIdx.x;
  const int wv = tid >> 6, ln = tid & 63;
  const int wr = wv >> 2, wc = wv & 3;         // 2 x 4 wave grid
  // XCD-bijective swizzle of the 8x32 tile grid (nwg=256, 256%8==0)
  const int bid = blockIdx.x + (blockIdx.y << 3);
  const int sw = (bid & 7) * 32 + (bid >> 3);
  const int row0 = (sw >> 3) * 256, col0 = (sw & 7) * 256;
  const int s_rw = tid >> 2;
  const int s_slotL = (tid & 3) ^ ((s_rw >> 1) & 3);   // logical slot fetched
  int aoff[8], boff[4];
  #pragma unroll
  for (int m = 0; m < 8; ++m) {
    int row = wr * 128 + m * 16 + (ln & 15);
    aoff[m] = row * 32 + swzslot(row, ln >> 4) * 8;
  }
  #pragma unroll
  for (int n = 0; n < 4; ++n) {
    int row = wc * 64 + n * 16 + (ln & 15);
    boff[n] = row * 32 + swzslot(row, ln >> 4) * 8;
  }
  f32x4 acc[8][4];
  #pragma unroll
  for (int m = 0; m < 8; ++m)
    #pragma unroll
    for (int n = 0; n < 4; ++n) acc[m][n] = (f32x4){0.f, 0.f, 0.f, 0.f};

  auto bufA = [&](int b) -> u16* { return (u16*)smem + b * 16384; };
  auto bufB = [&](int b) -> u16* { return (u16*)smem + b * 16384 + 8192; };
  auto stageA = [&](int kt, int b, int rblk) {
    const u16* g = A + (size_t)(row0 + rblk * 128 + s_rw) * 2048 + kt * 32 + s_slotL * 8;
    gld16(g, bufA(b) + rblk * 4096 + wv * 512);
  };
  auto stageB = [&](int kt, int b, int rblk) {
    const u16* g = Bw + (size_t)(col0 + rblk * 128 + s_rw) * 2048 + kt * 32 + s_slotL * 8;
    gld16(g, bufB(b) + rblk * 4096 + wv * 512);
  };

  // prologue: tiles 0,1 into buffers 0,1 (per-wave issue order: t0's 4 then t1's 4)
  stageA(0, 0, 0); stageA(0, 0, 1); stageB(0, 0, 0); stageB(0, 0, 1);
  stageA(1, 1, 0); stageA(1, 1, 1); stageB(1, 1, 0); stageB(1, 1, 1);

  int b = 0;
  for (int kt = 0; kt < 64; ++kt) {
    // retire exactly tile kt's 4 loads; tile kt+1's stay in flight
    if (kt < 63) asm volatile("s_waitcnt vmcnt(4)" ::: "memory");
    else         asm volatile("s_waitcnt vmcnt(0)" ::: "memory");
    __builtin_amdgcn_s_barrier();
    const u16* Ab = bufA(b);
    const u16* Bb = bufB(b);
    int b2 = b + 2; if (b2 >= 3) b2 -= 3;   // buffer for tile kt+2
    const bool st = (kt + 2) < 64;
    bf16x8 bf[4], af[4];
    #pragma unroll
    for (int n = 0; n < 4; ++n) bf[n] = *(const bf16x8*)(Bb + boff[n]);
    #pragma unroll
    for (int m = 0; m < 4; ++m) af[m] = *(const bf16x8*)(Ab + aoff[m]);
    if (st) { stageA(kt + 2, b2, 0); stageA(kt + 2, b2, 1); }
    __builtin_amdgcn_s_setprio(1);
    #pragma unroll
    for (int m = 0; m < 4; ++m)
      #pragma unroll
      for (int n = 0; n < 4; ++n)
        acc[m][n] = __builtin_amdgcn_mfma_f32_16x16x32_bf16(af[m], bf[n], acc[m][n], 0, 0, 0);
    __builtin_amdgcn_s_setprio(0);
    __builtin_amdgcn_s_barrier();           // phase split (role diversity)
    #pragma unroll
    for (int m = 0; m < 4; ++m) af[m] = *(const bf16x8*)(Ab + aoff[4 + m]);
    if (st) { stageB(kt + 2, b2, 0); stageB(kt + 2, b2, 1); }
    __builtin_amdgcn_s_setprio(1);
    #pragma unroll
    for (int m = 0; m < 4; ++m)
      #pragma unroll
      for (int n = 0; n < 4; ++n)
        acc[4 + m][n] = __builtin_amdgcn_mfma_f32_16x16x32_bf16(af[m], bf[n], acc[4 + m][n], 0, 0, 0);
    __builtin_amdgcn_s_setprio(0);
    b = (b + 1 == 3) ? 0 : b + 1;
  }

  const int rowb = row0 + wr * 128 + ((ln >> 4) << 2);
  const int colb = col0 + wc * 64 + (ln & 15);
  #pragma unroll
  for (int m = 0; m < 8; ++m)
    #pragma unroll
    for (int n = 0; n < 4; ++n)
      #pragma unroll
      for (int qq = 0; qq < 4; ++qq) {
        int row = rowb + m * 16 + qq;
        int col = colb + n * 16;
        float val = acc[m][n][qq];
        if (pmode == 0) {
          ((float*)out)[(size_t)row * 2048 + col] = val;
        } else {
          int bq = row >> 12, tq = row & (T_LEN - 1);
          int hq = col >> 4, jq = col & 15;
          *(u16*)(out + (size_t)((bq * 128 + hq) * T_LEN + tq) * REC
                  + sbase + jq * sstr) = f2bf(val);
        }
      }
}

// ---------------- post-GEMM: LoRA-up, decay, v-mix, kk-norm (coalesced module mapping) ----------------
__global__ __launch_bounds__(256)
void post_gemm_k(const float* __restrict__ v_first, const float* __restrict__ lora8,
                 const float* __restrict__ w0, const float* __restrict__ w2,
                 const float* __restrict__ a0, const float* __restrict__ a2,
                 const float* __restrict__ v0, const float* __restrict__ v2,
                 const float* __restrict__ k_k, const float* __restrict__ k_a,
                 char* __restrict__ packed) {
  const int tg = blockIdx.x;          // 0..1023 (4 t each)
  const int mo = blockIdx.y;          // module 0..31 (64 channels)
  const int bq = blockIdx.z;
  const int tid = threadIdx.x;
  const int wv = tid >> 6, ln = tid & 63;
  const int t = tg * 4 + wv;
  const int cc = ln & 15;
  const int hq = mo * 4 + (ln >> 4);
  const int c = mo * 64 + ln;
  char* pb = packed + (size_t)((bq * 128 + hq) * T_LEN + t) * REC;
  const int rr = bq * T_LEN + t;
  u32 kr = *(const u32*)(pb + cc * 8 + 4);
  float kraw = bflo(kr);
  float vraw = bflo(*(const u16*)(pb + 192 + cc * 2));
  float vf = v_first[(size_t)rr * C_DIM + c];
  const float* lo = lora8 + (size_t)rr * 32;
  float wr_ = w0[c], ar_ = a0[c], vr_ = v0[c];
  #pragma unroll
  for (int l = 0; l < 8; ++l) {
    wr_ = fmaf(lo[l], w2[l * C_DIM + c], wr_);
    ar_ = fmaf(lo[8 + l], a2[l * C_DIM + c], ar_);
    vr_ = fmaf(lo[16 + l], v2[l * C_DIM + c], vr_);
  }
  float w_ = -log1pf(expf(-wr_)) - 0.5f;
  float dec = expf(-expf(w_));
  float a_ = 1.f / (1.f + expf(-ar_));
  float vm = 1.f / (1.f + expf(-vr_));
  float vnew = fmaf(vf - vraw, vm, vraw);
  float kk = kraw * k_k[c];
  float ss = red16(kk * kk);
  ss += __shfl_xor(ss, 16);
  ss += __shfl_xor(ss, 32);
  float sc = 1.f / fmaxf(sqrtf(ss), 1e-8f);
  float kn = kk * sc;
  u16 wa = f2bf(-kn);
  u16 wb = f2bf(kn * a_);
  u16 wk = f2bf(kraw * fmaf(a_ - 1.f, k_a[c], 1.f));
  *(u32*)(pb + cc * 8) = (u32)wa | ((u32)wb << 16);
  *(u32*)(pb + cc * 8 + 4) = (u32)wk | (kr & 0xffff0000u);
  *(u16*)(pb + 192 + cc * 2) = f2bf(vnew);
  *(float*)(pb + 128 + cc * 4) = dec;
}

// ---------------- sequential RWKV7 scan: 1 head / 4-wave block, 1 elem/lane ----------------
__device__ __forceinline__ void stage(const char* g, char* l, int wv, int ln) {
  gld16(g + wv * 1024 + ln * 16, l + wv * 1024);
  gld16(g + 4096 + wv * 1024 + ln * 16, l + 4096 + wv * 1024);
  gld16(g + 8192 + wv * 1024 + ln * 16, l + 8192 + wv * 1024);
  if (wv < 2) gld16(g + 12288 + wv * 1024 + ln * 16, l + 12288 + wv * 1024);
}

__global__ __launch_bounds__(256)
void scan_k(char* __restrict__ packed) {
  // 2 chunk halves + 1 KB pad so distance-4 over-reads stay in-bounds
  __shared__ __attribute__((aligned(16))) char bufm[2 * CHB + 1024];
  __shared__ __attribute__((aligned(16))) float ybuf[CH * 16];
  const int hb = blockIdx.x;
  const int tid = threadIdx.x;
  const int wv = tid >> 6, ln = tid & 63;
  const int j = ln & 15;
  const int i = wv * 4 + (ln >> 4);
  char* src = packed + (size_t)hb * (T_LEN * REC);
  float S = 0.f;
  stage(src, bufm, wv, ln);
  const int NC = T_LEN / CH;
  for (int c = 0; c < NC; ++c) {
    asm volatile("s_waitcnt vmcnt(0)" ::: "memory");
    __syncthreads();
    if (c + 1 < NC)
      stage(src + (size_t)(c + 1) * CHB, bufm + ((c + 1) & 1) * CHB, wv, ln);
    const char* Bp = bufm + (c & 1) * CHB;
    const char* p0 = Bp + j * 8;         // [a|b][k|r] packet, +t*REC
    const char* pd = Bp + 128 + j * 4;   // dec f32
    const char* pv = Bp + 192 + i * 2;   // v bf16
    // preload steps 0..3
    u32x2 kq[4]; float dq[4]; u32 vq[4];
    #pragma unroll
    for (int s = 0; s < 4; ++s) {
      kq[s] = *(const u32x2*)(p0 + s * REC);
      dq[s] = *(const float*)(pd + s * REC);
      vq[s] = *(const u16*)(pv + s * REC);
    }
    float yq0 = 0.f, yq1 = 0.f, yq2 = 0.f, yq3 = 0.f;
    #pragma unroll
    for (int t = 0; t < CH; ++t) {
      const int st = t & 3;
      u32x2 kc = kq[st]; float dc = dq[st]; u32 vc = vq[st];
      // prefetch t+4 (tail over-reads land in pad; re-preloaded next chunk)
      kq[st] = *(const u32x2*)(p0 + (t + 4) * REC);
      dq[st] = *(const float*)(pd + (t + 4) * REC);
      vq[st] = *(const u16*)(pv + (t + 4) * REC);
      float a_ = bflo(kc[0]), b_ = bfhi(kc[0]);
      float k_ = bflo(kc[1]), r_ = bfhi(kc[1]);
      float v_ = bflo(vc);
      float sa = red16(S * a_);
      S = fmaf(S, dc, fmaf(sa, b_, v_ * k_));
      float yv = red16(S * r_);
      const bool own = (j == (t & 15));
      if ((t >> 4) == 0)      yq0 = own ? yv : yq0;
      else if ((t >> 4) == 1) yq1 = own ? yv : yq1;
      else if ((t >> 4) == 2) yq2 = own ? yv : yq2;
      else                    yq3 = own ? yv : yq3;
    }
    // dump register y to ybuf: value yqQ holds y for (t = Q*16 + j, row i)
    ybuf[(0 * 16 + j) * 16 + i] = yq0;
    ybuf[(1 * 16 + j) * 16 + i] = yq1;
    ybuf[(2 * 16 + j) * 16 + i] = yq2;
    ybuf[(3 * 16 + j) * 16 + i] = yq3;
    __syncthreads();
    // coalesced y flush: thread -> record tid>>2, 16B part tid&3
    {
      const int rec = tid >> 2, part = tid & 3;
      f32x4 y4 = *(const f32x4*)(ybuf + rec * 16 + part * 4);
      *(f32x4*)(src + (size_t)c * CHB + rec * REC + 128 + part * 16) = y4;
    }
  }
}

// ---------------- GroupNorm + residual + gate -> bf16 (coalesced module mapping) ----------------
__global__ __launch_bounds__(256)
void post_gn_k(const char* __restrict__ packed, const float* __restrict__ lora8,
               const float* __restrict__ g2, const float* __restrict__ ln_g,
               const float* __restrict__ ln_b, const float* __restrict__ r_k,
               u16* __restrict__ og) {
  const int tg = blockIdx.x;          // 0..1023 (4 t each)
  const int mo = blockIdx.y;          // module 0..31 (64 channels)
  const int bq = blockIdx.z;
  const int tid = threadIdx.x;
  const int wv = tid >> 6, ln = tid & 63;
  const int t = tg * 4 + wv;
  const int cc = ln & 15;
  const int hq = mo * 4 + (ln >> 4);
  const int c = mo * 64 + ln;
  const char* pb = packed + (size_t)((bq * 128 + hq) * T_LEN + t) * REC;
  u32 kr = *(const u32*)(pb + cc * 8 + 4);
  float kv = bflo(kr), rv = bfhi(kr);
  float vv = bflo(*(const u16*)(pb + 192 + cc * 2));
  float o = *(const float*)(pb + 128 + cc * 4);
  const int rr = bq * T_LEN + t;
  const float* lo = lora8 + (size_t)rr * 32 + 24;
  float gg = 0.f;
  #pragma unroll
  for (int l = 0; l < 8; ++l) gg = fmaf(lo[l], g2[l * C_DIM + c], gg);
  float s1 = red16(o);
  float s2 = red16(o * o);
  float srk = red16(rv * kv * r_k[c]);
  s1 += __shfl_xor(s1, 16); s2 += __shfl_xor(s2, 16); srk += __shfl_xor(srk, 16);
  s1 += __shfl_xor(s1, 32); s2 += __shfl_xor(s2, 32); srk += __shfl_xor(srk, 32);
  float mu = s1 * (1.f / 64.f);
  float var = s2 * (1.f / 64.f) - mu * mu;
  float rstd = rsqrtf(var + 0.00064f);
  float on = fmaf((o - mu) * rstd, ln_g[c], ln_b[c]);
  float o2 = fmaf(srk, vv, on);
  og[(size_t)rr * C_DIM + c] = f2bf(o2 * gg);
}

extern "C" void kernel_launch(void* const* d_in, const int* in_sizes, int n_in,
                              void* d_out, int out_size, void* d_ws, size_t ws_size,
                              hipStream_t stream) {
  (void)in_sizes; (void)n_in; (void)out_size;
  const float* x      = (const float*)d_in[0];
  const float* v_first= (const float*)d_in[1];
  const float* x_r    = (const float*)d_in[2];
  const float* x_w    = (const float*)d_in[3];
  const float* x_k    = (const float*)d_in[4];
  const float* x_v    = (const float*)d_in[5];
  const float* x_a    = (const float*)d_in[6];
  const float* x_g    = (const float*)d_in[7];
  const float* w0     = (const float*)d_in[8];
  const float* w1     = (const float*)d_in[9];
  const float* w2     = (const float*)d_in[10];
  const float* a0     = (const float*)d_in[11];
  const float* a1     = (const float*)d_in[12];
  const float* a2     = (const float*)d_in[13];
  const float* v0     = (const float*)d_in[14];
  const float* v1     = (const float*)d_in[15];
  const float* v2     = (const float*)d_in[16];
  const float* g1     = (const float*)d_in[17];
  const float* g2     = (const float*)d_in[18];
  const float* k_k    = (const float*)d_in[19];
  const float* k_a    = (const float*)d_in[20];
  const float* r_k    = (const float*)d_in[21];
  const float* Wr     = (const float*)d_in[22];
  const float* Wk     = (const float*)d_in[23];
  const float* Wv     = (const float*)d_in[24];
  const float* Wo     = (const float*)d_in[25];
  const float* ln_g   = (const float*)d_in[26];
  const float* ln_b   = (const float*)d_in[27];

  if (ws_size < 370147328ull) return;
  char* ws = (char*)d_ws;
  u16* Wr_bf = (u16*)(ws + 0);            //  8 MB each, contiguous (conv indexes)
  u16* Wk_bf = Wr_bf + 4194304;
  u16* Wv_bf = Wk_bf + 4194304;
  u16* Wo_bf = Wv_bf + 4194304;
  u16* xr_bf = (u16*)(ws + 33554432);     // 32 MB each
  u16* xk_bf = xr_bf + 16777216;
  u16* xv_bf = xk_bf + 16777216;
  float* lora8 = (float*)(ws + 134217728); // 1 MB
  char* packed = ws + 135266304;           // 224 MB
  float* wt = (float*)packed;              // transposed LoRA tables (256 KB),
                                           // consumed before gemms overwrite
  u16* og = xr_bf;                         // reuse (dead after r-GEMM)
  float* out = (float*)d_out;

  (void)hipFuncSetAttribute((const void*)gemm8_k,
                            hipFuncAttributeMaxDynamicSharedMemorySize, 98304);

  conv_bf16_k<<<dim3(2048, 4), 256, 0, stream>>>(Wr, Wk, Wv, Wo, Wr_bf);
  trans_lora_k<<<dim3(8, 4), 256, 0, stream>>>(w1, a1, v1, g1, wt);

  mix_lora_k<<<4096, 256, 0, stream>>>(x, x_r, x_w, x_k, x_v, x_a, x_g,
                                       wt, xr_bf, xk_bf, xv_bf, lora8);

  gemm8_k<<<dim3(8, 32, 3), 512, 98304, stream>>>(xk_bf, xr_bf, xv_bf,
                                                  Wk_bf, Wr_bf, Wv_bf,
                                                  packed, 1);

  post_gemm_k<<<dim3(1024, 32, 2), 256, 0, stream>>>(v_first, lora8, w0, w2,
                                                     a0, a2, v0, v2,
                                                     k_k, k_a, packed);

  scan_k<<<256, 256, 0, stream>>>(packed);

  post_gn_k<<<dim3(1024, 32, 2), 256, 0, stream>>>(packed, lora8, g2,
                                                   ln_g, ln_b, r_k, og);

  gemm8_k<<<dim3(8, 32, 1), 512, 98304, stream>>>(og, og, og,
                                                  Wo_bf, Wo_bf, Wo_bf,
                                                  (char*)out, 0);

  hipMemcpyAsync(out + 16777216, v_first, (size_t)16777216 * 4,
                 hipMemcpyDeviceToDevice, stream);
}